// Round 1
// baseline (963.290 us; speedup 1.0000x reference)
//
#include <hip/hip_runtime.h>
#include <hip/hip_bf16.h>
#include <math.h>

#define B_ 4
#define N_ 32768
#define CIN 6
#define C_ 64
#define R_ 16
#define S_ 4096

// ---------------- K1: voxelize scatter-add ----------------
__global__ void k_voxelize(const float* __restrict__ coords, const float* __restrict__ feats,
                           float* __restrict__ vsum, float* __restrict__ cnt) {
    int idx = blockIdx.x * 256 + threadIdx.x;      // B*N threads exactly
    int b = idx >> 15, n = idx & (N_ - 1);
    const float* cb = coords + (size_t)b * 3 * N_;
    float x = cb[n], y = cb[N_ + n], z = cb[2 * N_ + n];
    int vx = min(max((int)floorf(x * R_), 0), R_ - 1);
    int vy = min(max((int)floorf(y * R_), 0), R_ - 1);
    int vz = min(max((int)floorf(z * R_), 0), R_ - 1);
    int cell = (vx * R_ + vy) * R_ + vz;
    float* vs = vsum + (size_t)b * CIN * S_;
    const float* fb = feats + (size_t)b * CIN * N_;
#pragma unroll
    for (int f = 0; f < CIN; f++) atomicAdd(&vs[f * S_ + cell], fb[f * N_ + n]);
    atomicAdd(&cnt[b * S_ + cell], 1.0f);
}

// ---------------- K1b: divide by counts (in place) ----------------
__global__ void k_meandiv(float* __restrict__ vsum, const float* __restrict__ cnt) {
    int idx = blockIdx.x * 256 + threadIdx.x;      // B*CIN*S
    int b = idx / (CIN * S_);
    int cell = idx & (S_ - 1);
    float c = cnt[b * S_ + cell];
    vsum[idx] = vsum[idx] / fmaxf(c, 1.0f);
}

// ---------------- K2: 3x3x3 conv + bias + relu ----------------
__global__ void k_conv(const float* __restrict__ mean, const float* __restrict__ w,
                       const float* __restrict__ bias, float* __restrict__ outv) {
    __shared__ float wl[CIN * 27];
    int bo = blockIdx.x >> 4;       // (b*64+o)
    int chunk = blockIdx.x & 15;
    int b = bo >> 6, o = bo & 63;
    if (threadIdx.x < CIN * 27) wl[threadIdx.x] = w[o * CIN * 27 + threadIdx.x];
    __syncthreads();
    int cell = chunk * 256 + threadIdx.x;
    int x = cell >> 8, y = (cell >> 4) & 15, z = cell & 15;
    const float* mb = mean + (size_t)b * CIN * S_;
    float acc = bias[o];
#pragma unroll
    for (int dx = 0; dx < 3; dx++) {
        int xx = x + dx - 1;
        if ((unsigned)xx >= (unsigned)R_) continue;
#pragma unroll
        for (int dy = 0; dy < 3; dy++) {
            int yy = y + dy - 1;
            if ((unsigned)yy >= (unsigned)R_) continue;
#pragma unroll
            for (int dz = 0; dz < 3; dz++) {
                int zz = z + dz - 1;
                if ((unsigned)zz >= (unsigned)R_) continue;
                int nc = (xx * 16 + yy) * 16 + zz;
#pragma unroll
                for (int i = 0; i < CIN; i++)
                    acc += wl[i * 27 + dx * 9 + dy * 3 + dz] * mb[i * S_ + nc];
            }
        }
    }
    outv[((size_t)b * 64 + o) * S_ + cell] = fmaxf(acc, 0.0f);
}

// ---------------- K3: fused q/k/v projections ----------------
__global__ void k_qkv(const float* __restrict__ x, const float* __restrict__ wq,
                      const float* __restrict__ wk, const float* __restrict__ wv,
                      float* __restrict__ q, float* __restrict__ k, float* __restrict__ v) {
    __shared__ float wql[64], wkl[64], wvl[64];
    int blk = blockIdx.x;
    int b = blk >> 10;
    int rem = blk & 1023;
    int o = rem >> 4, chunk = rem & 15;
    if (threadIdx.x < 64) {
        wql[threadIdx.x] = wq[o * 64 + threadIdx.x];
        wkl[threadIdx.x] = wk[o * 64 + threadIdx.x];
        wvl[threadIdx.x] = wv[o * 64 + threadIdx.x];
    }
    __syncthreads();
    int s = chunk * 256 + threadIdx.x;
    const float* xb = x + (size_t)b * 64 * S_;
    float aq = 0.f, ak = 0.f, av = 0.f;
#pragma unroll 8
    for (int c = 0; c < 64; c++) {
        float xv = xb[c * S_ + s];
        aq += wql[c] * xv; ak += wkl[c] * xv; av += wvl[c] * xv;
    }
    size_t oidx = ((size_t)b * 64 + o) * S_ + s;
    q[oidx] = aq; k[oidx] = ak; v[oidx] = av;
}

// ---------------- K4: flash attention over voxel cells ----------------
__global__ __launch_bounds__(256) void k_attn(const float* __restrict__ q, const float* __restrict__ k,
                                              const float* __restrict__ v, float* __restrict__ pv) {
    __shared__ float qs[32][68];
    __shared__ float ks[64][68];
    __shared__ float vs[64][68];
    __shared__ float ps[32][68];
    int b = blockIdx.x >> 7;
    int s0 = (blockIdx.x & 127) * 32;
    int tid = threadIdx.x;
    const float* qb = q + (size_t)b * 64 * S_;
    const float* kb = k + (size_t)b * 64 * S_;
    const float* vb = v + (size_t)b * 64 * S_;
    for (int idx = tid; idx < 32 * 64; idx += 256) {
        int c = idx >> 5, r = idx & 31;
        qs[r][c] = qb[c * S_ + s0 + r];
    }
    int r = tid >> 3;            // row 0..31 (group of 8 threads)
    int c0 = (tid & 7) * 8;      // channel / t sub-block offset
    float m = -1e30f, l = 0.f;
    float O[8];
#pragma unroll
    for (int j = 0; j < 8; j++) O[j] = 0.f;
    __syncthreads();
    for (int t0 = 0; t0 < S_; t0 += 64) {
        for (int idx = tid; idx < 64 * 64; idx += 256) {
            int c = idx >> 6, t = idx & 63;
            ks[t][c] = kb[c * S_ + t0 + t];
            vs[t][c] = vb[c * S_ + t0 + t];
        }
        __syncthreads();
        float sc[8];
#pragma unroll
        for (int j = 0; j < 8; j++) sc[j] = 0.f;
#pragma unroll
        for (int c4 = 0; c4 < 16; c4++) {
            float4 qa = *(const float4*)&qs[r][c4 * 4];
#pragma unroll
            for (int j = 0; j < 8; j++) {
                float4 ka = *(const float4*)&ks[c0 + j][c4 * 4];
                sc[j] += qa.x * ka.x + qa.y * ka.y + qa.z * ka.z + qa.w * ka.w;
            }
        }
        float tm = -1e30f;
#pragma unroll
        for (int j = 0; j < 8; j++) { sc[j] *= 0.125f; tm = fmaxf(tm, sc[j]); }
        tm = fmaxf(tm, __shfl_xor(tm, 1));
        tm = fmaxf(tm, __shfl_xor(tm, 2));
        tm = fmaxf(tm, __shfl_xor(tm, 4));
        float mn = fmaxf(m, tm);
        float scale = __expf(m - mn);
        float psum = 0.f;
#pragma unroll
        for (int j = 0; j < 8; j++) {
            float p = __expf(sc[j] - mn);
            psum += p;
            ps[r][c0 + j] = p;
        }
        psum += __shfl_xor(psum, 1);
        psum += __shfl_xor(psum, 2);
        psum += __shfl_xor(psum, 4);
        l = l * scale + psum;
        m = mn;
#pragma unroll
        for (int j = 0; j < 8; j++) O[j] *= scale;
        __syncthreads();   // ps visible to full 8-lane group; score reads of ks done
#pragma unroll 4
        for (int t = 0; t < 64; t++) {
            float p = ps[r][t];
            float4 va = *(const float4*)&vs[t][c0];
            float4 vb4 = *(const float4*)&vs[t][c0 + 4];
            O[0] += p * va.x;  O[1] += p * va.y;  O[2] += p * va.z;  O[3] += p * va.w;
            O[4] += p * vb4.x; O[5] += p * vb4.y; O[6] += p * vb4.z; O[7] += p * vb4.w;
        }
        __syncthreads();   // done with ks/vs/ps before next tile overwrites
    }
    float inv = 1.f / l;
    size_t base = (size_t)b * 64 * S_ + s0 + r;
#pragma unroll
    for (int j = 0; j < 8; j++) pv[base + (size_t)(c0 + j) * S_] = O[j] * inv;
}

// ---------------- K5: wo projection + residual + SE mean partial ----------------
__global__ void k_wo_se(const float* __restrict__ pv, const float* __restrict__ wo,
                        const float* __restrict__ xin, float* __restrict__ xatt,
                        float* __restrict__ semean) {
    __shared__ float wl[64];
    __shared__ float red[256];
    int blk = blockIdx.x;
    int b = blk >> 10;
    int rem = blk & 1023;
    int o = rem >> 4, chunk = rem & 15;
    if (threadIdx.x < 64) wl[threadIdx.x] = wo[o * 64 + threadIdx.x];
    __syncthreads();
    int s = chunk * 256 + threadIdx.x;
    const float* pb = pv + (size_t)b * 64 * S_;
    float acc = 0.f;
#pragma unroll 8
    for (int c = 0; c < 64; c++) acc += wl[c] * pb[c * S_ + s];
    float xn = xin[((size_t)b * 64 + o) * S_ + s] + acc;
    xatt[((size_t)b * 64 + o) * S_ + s] = xn;
    red[threadIdx.x] = xn;
    __syncthreads();
    for (int off = 128; off > 0; off >>= 1) {
        if (threadIdx.x < off) red[threadIdx.x] += red[threadIdx.x + off];
        __syncthreads();
    }
    if (threadIdx.x == 0) atomicAdd(&semean[b * 64 + o], red[0]);
}

// ---------------- K6: SE gate ----------------
__global__ void k_gate(const float* __restrict__ semean, const float* __restrict__ w1,
                       const float* __restrict__ b1, const float* __restrict__ w2,
                       const float* __restrict__ b2, float* __restrict__ gate) {
    __shared__ float sm[64];
    __shared__ float hh[8];
    int b = blockIdx.x, c = threadIdx.x;
    sm[c] = semean[b * 64 + c] * (1.0f / S_);
    __syncthreads();
    if (c < 8) {
        float a = b1[c];
        for (int i = 0; i < 64; i++) a += w1[c * 64 + i] * sm[i];
        hh[c] = fmaxf(a, 0.f);
    }
    __syncthreads();
    float g = b2[c];
#pragma unroll
    for (int j = 0; j < 8; j++) g += w2[c * 8 + j] * hh[j];
    gate[b * 64 + c] = 1.f / (1.f + __expf(-g));
}

// ---------------- K7: gate + transpose to [B][S][C] ----------------
__global__ void k_transpose(const float* __restrict__ xatt, const float* __restrict__ gate,
                            float* __restrict__ xt) {
    int idx = blockIdx.x * 256 + threadIdx.x;   // B*S*64
    int b = idx >> 18;
    int rem = idx & 262143;
    int s = rem >> 6, c = rem & 63;
    xt[idx] = xatt[((size_t)b * 64 + c) * S_ + s] * gate[b * 64 + c];
}

// ---------------- K8: devoxelize + point MLP + classifier ----------------
__global__ __launch_bounds__(256) void k_point(const float* __restrict__ coords, const float* __restrict__ feats,
                                               const float* __restrict__ xt, const float* __restrict__ pw,
                                               const float* __restrict__ pb, const float* __restrict__ w1,
                                               const float* __restrict__ b1, const float* __restrict__ w2,
                                               const float* __restrict__ b2, float* __restrict__ out) {
    __shared__ float w1l[128 * 64];
    __shared__ float pwl[64 * 6];
    __shared__ float pbl[64];
    __shared__ float b1l[128];
    __shared__ float w2l[3 * 128];
    __shared__ float b2l[3];
    int tid = threadIdx.x;
    for (int i = tid; i < 128 * 64; i += 256) w1l[i] = w1[i];
    for (int i = tid; i < 384; i += 256) { pwl[i] = pw[i]; w2l[i] = w2[i]; }
    if (tid < 128) b1l[tid] = b1[tid];
    if (tid < 64) pbl[tid] = pb[tid];
    if (tid < 3) b2l[tid] = b2[tid];
    __syncthreads();
    int gidx = blockIdx.x * 256 + tid;
    int b = gidx >> 15, n = gidx & (N_ - 1);
    const float* cb = coords + (size_t)b * 3 * N_;
    float px = fminf(fmaxf(cb[n] * R_ - 0.5f, 0.f), 15.f);
    float py = fminf(fmaxf(cb[N_ + n] * R_ - 0.5f, 0.f), 15.f);
    float pz = fminf(fmaxf(cb[2 * N_ + n] * R_ - 0.5f, 0.f), 15.f);
    int x0 = (int)floorf(px); float wx = px - x0; int x1 = min(x0 + 1, 15);
    int y0 = (int)floorf(py); float wy = py - y0; int y1 = min(y0 + 1, 15);
    int z0 = (int)floorf(pz); float wz = pz - z0; int z1 = min(z0 + 1, 15);
    float fused[64];
#pragma unroll
    for (int c = 0; c < 64; c++) fused[c] = 0.f;
    const float* xb = xt + (size_t)b * S_ * 64;
#pragma unroll
    for (int dx = 0; dx < 2; dx++) {
#pragma unroll
        for (int dy = 0; dy < 2; dy++) {
#pragma unroll
            for (int dz = 0; dz < 2; dz++) {
                int xi = dx ? x1 : x0, yi = dy ? y1 : y0, zi = dz ? z1 : z0;
                float wgt = (dx ? wx : 1.f - wx) * (dy ? wy : 1.f - wy) * (dz ? wz : 1.f - wz);
                const float4* g = (const float4*)(xb + (size_t)((xi * 16 + yi) * 16 + zi) * 64);
#pragma unroll
                for (int c4 = 0; c4 < 16; c4++) {
                    float4 gv = g[c4];
                    fused[c4 * 4 + 0] += wgt * gv.x;
                    fused[c4 * 4 + 1] += wgt * gv.y;
                    fused[c4 * 4 + 2] += wgt * gv.z;
                    fused[c4 * 4 + 3] += wgt * gv.w;
                }
            }
        }
    }
    float fv[6];
#pragma unroll
    for (int i = 0; i < 6; i++) fv[i] = feats[((size_t)b * 6 + i) * N_ + n];
#pragma unroll
    for (int c = 0; c < 64; c++) {
        float pt = pbl[c];
#pragma unroll
        for (int i = 0; i < 6; i++) pt += pwl[c * 6 + i] * fv[i];
        pt = fmaxf(pt, 0.f);
        fused[c] = fmaxf(fused[c] + pt, 0.f);
    }
    float o0 = b2l[0], o1 = b2l[1], o2 = b2l[2];
    for (int j = 0; j < 128; j++) {
        float hj = b1l[j];
#pragma unroll
        for (int c4 = 0; c4 < 16; c4++) {
            float4 wv = *(const float4*)&w1l[j * 64 + c4 * 4];
            hj += wv.x * fused[c4 * 4] + wv.y * fused[c4 * 4 + 1] +
                  wv.z * fused[c4 * 4 + 2] + wv.w * fused[c4 * 4 + 3];
        }
        hj = fmaxf(hj, 0.f);
        o0 += w2l[j] * hj;
        o1 += w2l[128 + j] * hj;
        o2 += w2l[256 + j] * hj;
    }
    out[((size_t)b * 3 + 0) * N_ + n] = o0;
    out[((size_t)b * 3 + 1) * N_ + n] = o1;
    out[((size_t)b * 3 + 2) * N_ + n] = o2;
}

extern "C" void kernel_launch(void* const* d_in, const int* in_sizes, int n_in,
                              void* d_out, int out_size, void* d_ws, size_t ws_size,
                              hipStream_t stream) {
    const float* coords  = (const float*)d_in[0];
    const float* feats   = (const float*)d_in[1];
    const float* conv_w  = (const float*)d_in[2];
    const float* conv_b  = (const float*)d_in[3];
    const float* wq      = (const float*)d_in[4];
    const float* wk      = (const float*)d_in[5];
    const float* wv      = (const float*)d_in[6];
    const float* wo      = (const float*)d_in[7];
    const float* se_w1   = (const float*)d_in[8];
    const float* se_b1   = (const float*)d_in[9];
    const float* se_w2   = (const float*)d_in[10];
    const float* se_b2   = (const float*)d_in[11];
    const float* point_w = (const float*)d_in[12];
    const float* point_b = (const float*)d_in[13];
    const float* cls_w1  = (const float*)d_in[14];
    const float* cls_b1  = (const float*)d_in[15];
    const float* cls_w2  = (const float*)d_in[16];
    const float* cls_b2  = (const float*)d_in[17];

    float* ws = (float*)d_ws;
    float* vsum   = ws;                    // B*6*S   = 98304
    float* cnt    = ws + 98304;            // B*S     = 16384
    float* semean = ws + 114688;           // B*64    = 256
    float* gate   = ws + 114944;           // B*64    = 256
    float* vox    = ws + 115200;           // B*64*S  = 1048576 (conv out = attention input x)
    float* q      = vox + 1048576;
    float* k      = q + 1048576;
    float* v      = k + 1048576;
    float* pv     = v + 1048576;
    float* xatt   = k;   // k is dead after k_attn
    float* xt     = q;   // q is dead after k_attn

    hipMemsetAsync(ws, 0, 114944 * sizeof(float), stream);   // vsum+cnt+semean
    k_voxelize<<<512, 256, 0, stream>>>(coords, feats, vsum, cnt);
    k_meandiv<<<384, 256, 0, stream>>>(vsum, cnt);
    k_conv<<<4096, 256, 0, stream>>>(vsum, conv_w, conv_b, vox);
    k_qkv<<<4096, 256, 0, stream>>>(vox, wq, wk, wv, q, k, v);
    k_attn<<<512, 256, 0, stream>>>(q, k, v, pv);
    k_wo_se<<<4096, 256, 0, stream>>>(pv, wo, vox, xatt, semean);
    k_gate<<<4, 64, 0, stream>>>(semean, se_w1, se_b1, se_w2, se_b2, gate);
    k_transpose<<<4096, 256, 0, stream>>>(xatt, gate, xt);
    k_point<<<512, 256, 0, stream>>>(coords, feats, xt, point_w, point_b,
                                     cls_w1, cls_b1, cls_w2, cls_b2, (float*)d_out);
}

// Round 2
// 399.717 us; speedup vs baseline: 2.4099x; 2.4099x over previous
//
#include <hip/hip_runtime.h>
#include <hip/hip_bf16.h>
#include <math.h>

#define B_ 4
#define N_ 32768
#define CIN 6
#define C_ 64
#define R_ 16
#define S_ 4096

typedef __attribute__((ext_vector_type(8))) __bf16 bf16x8;
typedef __attribute__((ext_vector_type(8))) short short8;
typedef __attribute__((ext_vector_type(4))) float f32x4;

#define MFMA16(a, b, c) __builtin_amdgcn_mfma_f32_16x16x32_bf16((a), (b), (c), 0, 0, 0)

__device__ inline unsigned short f2bf(float f) {
    unsigned u = __builtin_bit_cast(unsigned, f);
    u += 0x7fffu + ((u >> 16) & 1u);          // RNE
    return (unsigned short)(u >> 16);
}

// ---------------- K1: voxelize scatter-add ----------------
__global__ void k_voxelize(const float* __restrict__ coords, const float* __restrict__ feats,
                           float* __restrict__ vsum, float* __restrict__ cnt) {
    int idx = blockIdx.x * 256 + threadIdx.x;
    int b = idx >> 15, n = idx & (N_ - 1);
    const float* cb = coords + (size_t)b * 3 * N_;
    float x = cb[n], y = cb[N_ + n], z = cb[2 * N_ + n];
    int vx = min(max((int)floorf(x * R_), 0), R_ - 1);
    int vy = min(max((int)floorf(y * R_), 0), R_ - 1);
    int vz = min(max((int)floorf(z * R_), 0), R_ - 1);
    int cell = (vx * R_ + vy) * R_ + vz;
    float* vs = vsum + (size_t)b * CIN * S_;
    const float* fb = feats + (size_t)b * CIN * N_;
#pragma unroll
    for (int f = 0; f < CIN; f++) atomicAdd(&vs[f * S_ + cell], fb[f * N_ + n]);
    atomicAdd(&cnt[b * S_ + cell], 1.0f);
}

// ---------------- K1b: divide by counts ----------------
__global__ void k_meandiv(float* __restrict__ vsum, const float* __restrict__ cnt) {
    int idx = blockIdx.x * 256 + threadIdx.x;
    int b = idx / (CIN * S_);
    int cell = idx & (S_ - 1);
    float c = cnt[b * S_ + cell];
    vsum[idx] = vsum[idx] / fmaxf(c, 1.0f);
}

// ---------------- K2: 3x3x3 conv + bias + relu ----------------
__global__ void k_conv(const float* __restrict__ mean, const float* __restrict__ w,
                       const float* __restrict__ bias, float* __restrict__ outv) {
    __shared__ float wl[CIN * 27];
    int bo = blockIdx.x >> 4;
    int chunk = blockIdx.x & 15;
    int b = bo >> 6, o = bo & 63;
    if (threadIdx.x < CIN * 27) wl[threadIdx.x] = w[o * CIN * 27 + threadIdx.x];
    __syncthreads();
    int cell = chunk * 256 + threadIdx.x;
    int x = cell >> 8, y = (cell >> 4) & 15, z = cell & 15;
    const float* mb = mean + (size_t)b * CIN * S_;
    float acc = bias[o];
#pragma unroll
    for (int dx = 0; dx < 3; dx++) {
        int xx = x + dx - 1;
        if ((unsigned)xx >= (unsigned)R_) continue;
#pragma unroll
        for (int dy = 0; dy < 3; dy++) {
            int yy = y + dy - 1;
            if ((unsigned)yy >= (unsigned)R_) continue;
#pragma unroll
            for (int dz = 0; dz < 3; dz++) {
                int zz = z + dz - 1;
                if ((unsigned)zz >= (unsigned)R_) continue;
                int nc = (xx * 16 + yy) * 16 + zz;
#pragma unroll
                for (int i = 0; i < CIN; i++)
                    acc += wl[i * 27 + dx * 9 + dy * 3 + dz] * mb[i * S_ + nc];
            }
        }
    }
    outv[((size_t)b * 64 + o) * S_ + cell] = fmaxf(acc, 0.0f);
}

// ---------------- K3: q/k/v projections -> qT,kT bf16 [b][s][64]; v f32 [b][c][s] ----------------
__global__ __launch_bounds__(256) void k_qkv2(const float* __restrict__ x, const float* __restrict__ wq,
                                              const float* __restrict__ wk, const float* __restrict__ wv,
                                              unsigned short* __restrict__ qT, unsigned short* __restrict__ kT,
                                              float* __restrict__ vout) {
    __shared__ float wql[32 * 64], wkl[32 * 64], wvl[32 * 64];
    int blk = blockIdx.x;                 // 128 blocks: b(4) x schunk(16) x ohalf(2)
    int b = blk >> 5;
    int schunk = (blk >> 1) & 15;
    int o0 = (blk & 1) * 32;
    int tid = threadIdx.x;
    for (int i = tid; i < 2048; i += 256) {
        wql[i] = wq[o0 * 64 + i];
        wkl[i] = wk[o0 * 64 + i];
        wvl[i] = wv[o0 * 64 + i];
    }
    __syncthreads();
    int sb = schunk * 256 + tid;          // s within batch
    const float* xb = x + (size_t)b * 64 * S_;
    float xr[64];
#pragma unroll
    for (int c = 0; c < 64; c++) xr[c] = xb[c * S_ + sb];
    unsigned short* qrow = qT + ((size_t)b * S_ + sb) * 64 + o0;
    unsigned short* krow = kT + ((size_t)b * S_ + sb) * 64 + o0;
#pragma unroll
    for (int og = 0; og < 4; og++) {
        short8 sq, sk;
#pragma unroll
        for (int oj = 0; oj < 8; oj++) {
            int oi = og * 8 + oj;
            float aq = 0.f, ak = 0.f, av = 0.f;
#pragma unroll
            for (int c = 0; c < 64; c++) {
                float xv = xr[c];
                aq += wql[oi * 64 + c] * xv;
                ak += wkl[oi * 64 + c] * xv;
                av += wvl[oi * 64 + c] * xv;
            }
            sq[oj] = (short)f2bf(aq);
            sk[oj] = (short)f2bf(ak);
            vout[((size_t)b * 64 + o0 + oi) * S_ + sb] = av;
        }
        *(short8*)(qrow + og * 8) = sq;
        *(short8*)(krow + og * 8) = sk;
    }
}

// ---------------- K4: MFMA flash attention ----------------
__global__ __launch_bounds__(256) void k_attn_mfma(const unsigned short* __restrict__ qT,
                                                   const unsigned short* __restrict__ kT,
                                                   const float* __restrict__ v,
                                                   float* __restrict__ pvT) {
    __shared__ unsigned short Ks[64 * 64];      // [t][chan] swizzled
    __shared__ unsigned short Vs[64 * 64];      // [chan][t] swizzled
    __shared__ unsigned short Ps[4][16 * 64];   // per-wave [r][t] swizzled
    int b = blockIdx.x >> 6;
    int s0 = (blockIdx.x & 63) * 64;
    int tid = threadIdx.x;
    int wid = tid >> 6, lane = tid & 63;
    int lo = lane & 15, hi = lane >> 4;

    // Q fragments (A): row = lo, chan = hi*8 + i (+32)
    const unsigned short* qb = qT + ((size_t)b * S_ + s0 + wid * 16) * 64;
    bf16x8 qf0 = __builtin_bit_cast(bf16x8, *(const short8*)(qb + lo * 64 + hi * 8));
    bf16x8 qf1 = __builtin_bit_cast(bf16x8, *(const short8*)(qb + lo * 64 + hi * 8 + 32));

    f32x4 O[4];
    float m[4], l[4];
#pragma unroll
    for (int cc = 0; cc < 4; cc++) O[cc] = (f32x4){0.f, 0.f, 0.f, 0.f};
#pragma unroll
    for (int j = 0; j < 4; j++) { m[j] = -1e30f; l[j] = 0.f; }

    // staging assignments
    int st = tid >> 2, sc = (tid & 3) * 16;       // K: row st, chans sc..sc+15
    const unsigned short* kbase = kT + ((size_t)b * S_) * 64;
    const float* vbase = v + ((size_t)b * 64 + (tid >> 2)) * S_ + (tid & 3) * 16;

    for (int t0 = 0; t0 < S_; t0 += 64) {
        // ---- stage K tile ----
        {
            const unsigned short* ksrc = kbase + (size_t)(t0 + st) * 64 + sc;
            short8 k0 = *(const short8*)(ksrc);
            short8 k1 = *(const short8*)(ksrc + 8);
            int swz = (st & 7) << 4;
            *(short8*)((char*)Ks + ((st * 128 + sc * 2) ^ swz)) = k0;
            *(short8*)((char*)Ks + ((st * 128 + sc * 2 + 16) ^ swz)) = k1;
        }
        // ---- stage V tile (f32 -> bf16) ----
        {
            int c = tid >> 2, tc0 = (tid & 3) * 16;
            const float* vsrc = vbase + t0;
            float4 f0 = *(const float4*)(vsrc + 0);
            float4 f1 = *(const float4*)(vsrc + 4);
            float4 f2 = *(const float4*)(vsrc + 8);
            float4 f3 = *(const float4*)(vsrc + 12);
            short8 p0, p1;
            p0[0] = (short)f2bf(f0.x); p0[1] = (short)f2bf(f0.y); p0[2] = (short)f2bf(f0.z); p0[3] = (short)f2bf(f0.w);
            p0[4] = (short)f2bf(f1.x); p0[5] = (short)f2bf(f1.y); p0[6] = (short)f2bf(f1.z); p0[7] = (short)f2bf(f1.w);
            p1[0] = (short)f2bf(f2.x); p1[1] = (short)f2bf(f2.y); p1[2] = (short)f2bf(f2.z); p1[3] = (short)f2bf(f2.w);
            p1[4] = (short)f2bf(f3.x); p1[5] = (short)f2bf(f3.y); p1[6] = (short)f2bf(f3.z); p1[7] = (short)f2bf(f3.w);
            int swz = (c & 7) << 4;
            *(short8*)((char*)Vs + ((c * 128 + tc0 * 2) ^ swz)) = p0;
            *(short8*)((char*)Vs + ((c * 128 + tc0 * 2 + 16) ^ swz)) = p1;
        }
        __syncthreads();

        // ---- QK^T: 4 t-col tiles ----
        f32x4 Sacc[4];
#pragma unroll
        for (int ct = 0; ct < 4; ct++) {
            Sacc[ct] = (f32x4){0.f, 0.f, 0.f, 0.f};
            int t = ct * 16 + lo;
            int swz = (t & 7) << 4;
            bf16x8 kf0 = __builtin_bit_cast(bf16x8, *(const short8*)((char*)Ks + ((t * 128 + hi * 16) ^ swz)));
            bf16x8 kf1 = __builtin_bit_cast(bf16x8, *(const short8*)((char*)Ks + ((t * 128 + hi * 16 + 64) ^ swz)));
            Sacc[ct] = MFMA16(qf0, kf0, Sacc[ct]);
            Sacc[ct] = MFMA16(qf1, kf1, Sacc[ct]);
        }

        // ---- online softmax (rows = hi*4 + j, cols across lo & ct) ----
#pragma unroll
        for (int j = 0; j < 4; j++) {
            float tm = Sacc[0][j];
            tm = fmaxf(tm, Sacc[1][j]);
            tm = fmaxf(tm, Sacc[2][j]);
            tm = fmaxf(tm, Sacc[3][j]);
            tm *= 0.125f;
            tm = fmaxf(tm, __shfl_xor(tm, 1));
            tm = fmaxf(tm, __shfl_xor(tm, 2));
            tm = fmaxf(tm, __shfl_xor(tm, 4));
            tm = fmaxf(tm, __shfl_xor(tm, 8));
            float mn = fmaxf(m[j], tm);
            float esc = __expf(m[j] - mn);
            m[j] = mn;
            int r = hi * 4 + j;
            int swz = (r & 7) << 4;
            float psum = 0.f;
#pragma unroll
            for (int ct = 0; ct < 4; ct++) {
                float p = __expf(Sacc[ct][j] * 0.125f - mn);
                psum += p;
                int t = ct * 16 + lo;
                *(unsigned short*)((char*)&Ps[wid][0] + ((r * 128 + t * 2) ^ swz)) = f2bf(p);
            }
            psum += __shfl_xor(psum, 1);
            psum += __shfl_xor(psum, 2);
            psum += __shfl_xor(psum, 4);
            psum += __shfl_xor(psum, 8);
            l[j] = l[j] * esc + psum;
            O[0][j] *= esc; O[1][j] *= esc; O[2][j] *= esc; O[3][j] *= esc;
        }

        // ---- P A-fragments: row = lo, t = tc*32 + hi*8 + i ----
        {
            int swz = (lo & 7) << 4;
            bf16x8 pa0 = __builtin_bit_cast(bf16x8, *(const short8*)((char*)&Ps[wid][0] + ((lo * 128 + hi * 16) ^ swz)));
            bf16x8 pa1 = __builtin_bit_cast(bf16x8, *(const short8*)((char*)&Ps[wid][0] + ((lo * 128 + hi * 16 + 64) ^ swz)));
#pragma unroll
            for (int cc = 0; cc < 4; cc++) {
                int c = cc * 16 + lo;
                int vswz = (c & 7) << 4;
                bf16x8 vf0 = __builtin_bit_cast(bf16x8, *(const short8*)((char*)Vs + ((c * 128 + hi * 16) ^ vswz)));
                bf16x8 vf1 = __builtin_bit_cast(bf16x8, *(const short8*)((char*)Vs + ((c * 128 + hi * 16 + 64) ^ vswz)));
                O[cc] = MFMA16(pa0, vf0, O[cc]);
                O[cc] = MFMA16(pa1, vf1, O[cc]);
            }
        }
        __syncthreads();
    }

    float inv[4];
#pragma unroll
    for (int j = 0; j < 4; j++) inv[j] = 1.f / l[j];
    float* orow = pvT + ((size_t)b * S_ + s0 + wid * 16) * 64;
#pragma unroll
    for (int cc = 0; cc < 4; cc++)
#pragma unroll
        for (int j = 0; j < 4; j++)
            orow[(size_t)(hi * 4 + j) * 64 + cc * 16 + lo] = O[cc][j] * inv[j];
}

// ---------------- K5: wo projection + residual ----------------
__global__ __launch_bounds__(256) void k_wo(const float* __restrict__ pvT, const float* __restrict__ wo,
                                            const float* __restrict__ xin, float* __restrict__ xatt) {
    __shared__ float wl[64 * 64];
    int tid = threadIdx.x;
    for (int i = tid; i < 4096; i += 256) wl[i] = wo[i];
    __syncthreads();
    int gid = blockIdx.x * 256 + tid;
    int b = gid >> 12, s = gid & 4095;
    const float4* pp = (const float4*)(pvT + ((size_t)b * S_ + s) * 64);
    float pr[64];
#pragma unroll
    for (int i = 0; i < 16; i++) {
        float4 t = pp[i];
        pr[i * 4 + 0] = t.x; pr[i * 4 + 1] = t.y; pr[i * 4 + 2] = t.z; pr[i * 4 + 3] = t.w;
    }
    for (int o = 0; o < 64; o++) {
        float acc = 0.f;
#pragma unroll
        for (int c4 = 0; c4 < 16; c4++) {
            float4 w4 = *(const float4*)&wl[o * 64 + c4 * 4];
            acc += w4.x * pr[c4 * 4] + w4.y * pr[c4 * 4 + 1] + w4.z * pr[c4 * 4 + 2] + w4.w * pr[c4 * 4 + 3];
        }
        size_t oi = ((size_t)b * 64 + o) * S_ + s;
        xatt[oi] = xin[oi] + acc;
    }
}

// ---------------- K5b: SE channel means ----------------
__global__ void k_semean(const float* __restrict__ xatt, float* __restrict__ semean) {
    __shared__ float red[256];
    int blk = blockIdx.x;                 // b*64 + o
    const float* base = xatt + (size_t)blk * S_;
    int tid = threadIdx.x;
    float acc = 0.f;
#pragma unroll
    for (int i = 0; i < 16; i++) acc += base[i * 256 + tid];
    red[tid] = acc;
    __syncthreads();
    for (int off = 128; off > 0; off >>= 1) {
        if (tid < off) red[tid] += red[tid + off];
        __syncthreads();
    }
    if (tid == 0) semean[blk] = red[0];
}

// ---------------- K6: SE gate ----------------
__global__ void k_gate(const float* __restrict__ semean, const float* __restrict__ w1,
                       const float* __restrict__ b1, const float* __restrict__ w2,
                       const float* __restrict__ b2, float* __restrict__ gate) {
    __shared__ float sm[64];
    __shared__ float hh[8];
    int b = blockIdx.x, c = threadIdx.x;
    sm[c] = semean[b * 64 + c] * (1.0f / S_);
    __syncthreads();
    if (c < 8) {
        float a = b1[c];
        for (int i = 0; i < 64; i++) a += w1[c * 64 + i] * sm[i];
        hh[c] = fmaxf(a, 0.f);
    }
    __syncthreads();
    float g = b2[c];
#pragma unroll
    for (int j = 0; j < 8; j++) g += w2[c * 8 + j] * hh[j];
    gate[b * 64 + c] = 1.f / (1.f + __expf(-g));
}

// ---------------- K7: gate + transpose via LDS -> xt [b][s][64] ----------------
__global__ __launch_bounds__(256) void k_transpose2(const float* __restrict__ xatt,
                                                    const float* __restrict__ gate,
                                                    float* __restrict__ xt) {
    __shared__ float T[64][65];
    int b = blockIdx.x >> 6;
    int sb0 = (blockIdx.x & 63) * 64;
    int tid = threadIdx.x;
    int c = tid >> 2, sc0 = (tid & 3) * 16;
    float g = gate[b * 64 + c];
    const float* src = xatt + ((size_t)b * 64 + c) * S_ + sb0 + sc0;
#pragma unroll
    for (int k = 0; k < 4; k++) {
        float4 r = *(const float4*)(src + 4 * k);
        T[c][sc0 + 4 * k + 0] = r.x * g;
        T[c][sc0 + 4 * k + 1] = r.y * g;
        T[c][sc0 + 4 * k + 2] = r.z * g;
        T[c][sc0 + 4 * k + 3] = r.w * g;
    }
    __syncthreads();
#pragma unroll
    for (int k = 0; k < 4; k++) {
        int idx = tid + k * 256;
        int s = idx >> 4, c0 = (idx & 15) * 4;
        float4 o;
        o.x = T[c0 + 0][s]; o.y = T[c0 + 1][s]; o.z = T[c0 + 2][s]; o.w = T[c0 + 3][s];
        *(float4*)(xt + ((size_t)b * S_ + sb0 + s) * 64 + c0) = o;
    }
}

// ---------------- K8: devoxelize + point MLP + classifier ----------------
__global__ __launch_bounds__(256) void k_point(const float* __restrict__ coords, const float* __restrict__ feats,
                                               const float* __restrict__ xt, const float* __restrict__ pw,
                                               const float* __restrict__ pb, const float* __restrict__ w1,
                                               const float* __restrict__ b1, const float* __restrict__ w2,
                                               const float* __restrict__ b2, float* __restrict__ out) {
    __shared__ float w1l[128 * 64];
    __shared__ float pwl[64 * 6];
    __shared__ float pbl[64];
    __shared__ float b1l[128];
    __shared__ float w2l[3 * 128];
    __shared__ float b2l[3];
    int tid = threadIdx.x;
    for (int i = tid; i < 128 * 64; i += 256) w1l[i] = w1[i];
    for (int i = tid; i < 384; i += 256) { pwl[i] = pw[i]; w2l[i] = w2[i]; }
    if (tid < 128) b1l[tid] = b1[tid];
    if (tid < 64) pbl[tid] = pb[tid];
    if (tid < 3) b2l[tid] = b2[tid];
    __syncthreads();
    int gidx = blockIdx.x * 256 + tid;
    int b = gidx >> 15, n = gidx & (N_ - 1);
    const float* cb = coords + (size_t)b * 3 * N_;
    float px = fminf(fmaxf(cb[n] * R_ - 0.5f, 0.f), 15.f);
    float py = fminf(fmaxf(cb[N_ + n] * R_ - 0.5f, 0.f), 15.f);
    float pz = fminf(fmaxf(cb[2 * N_ + n] * R_ - 0.5f, 0.f), 15.f);
    int x0 = (int)floorf(px); float wx = px - x0; int x1 = min(x0 + 1, 15);
    int y0 = (int)floorf(py); float wy = py - y0; int y1 = min(y0 + 1, 15);
    int z0 = (int)floorf(pz); float wz = pz - z0; int z1 = min(z0 + 1, 15);
    float fused[64];
#pragma unroll
    for (int c = 0; c < 64; c++) fused[c] = 0.f;
    const float* xb = xt + (size_t)b * S_ * 64;
#pragma unroll
    for (int dx = 0; dx < 2; dx++) {
#pragma unroll
        for (int dy = 0; dy < 2; dy++) {
#pragma unroll
            for (int dz = 0; dz < 2; dz++) {
                int xi = dx ? x1 : x0, yi = dy ? y1 : y0, zi = dz ? z1 : z0;
                float wgt = (dx ? wx : 1.f - wx) * (dy ? wy : 1.f - wy) * (dz ? wz : 1.f - wz);
                const float4* g = (const float4*)(xb + (size_t)((xi * 16 + yi) * 16 + zi) * 64);
#pragma unroll
                for (int c4 = 0; c4 < 16; c4++) {
                    float4 gv = g[c4];
                    fused[c4 * 4 + 0] += wgt * gv.x;
                    fused[c4 * 4 + 1] += wgt * gv.y;
                    fused[c4 * 4 + 2] += wgt * gv.z;
                    fused[c4 * 4 + 3] += wgt * gv.w;
                }
            }
        }
    }
    float fv[6];
#pragma unroll
    for (int i = 0; i < 6; i++) fv[i] = feats[((size_t)b * 6 + i) * N_ + n];
#pragma unroll
    for (int c = 0; c < 64; c++) {
        float pt = pbl[c];
#pragma unroll
        for (int i = 0; i < 6; i++) pt += pwl[c * 6 + i] * fv[i];
        pt = fmaxf(pt, 0.f);
        fused[c] = fmaxf(fused[c] + pt, 0.f);
    }
    float o0 = b2l[0], o1 = b2l[1], o2 = b2l[2];
    for (int j = 0; j < 128; j++) {
        float hj = b1l[j];
#pragma unroll
        for (int c4 = 0; c4 < 16; c4++) {
            float4 wv = *(const float4*)&w1l[j * 64 + c4 * 4];
            hj += wv.x * fused[c4 * 4] + wv.y * fused[c4 * 4 + 1] +
                  wv.z * fused[c4 * 4 + 2] + wv.w * fused[c4 * 4 + 3];
        }
        hj = fmaxf(hj, 0.f);
        o0 += w2l[j] * hj;
        o1 += w2l[128 + j] * hj;
        o2 += w2l[256 + j] * hj;
    }
    out[((size_t)b * 3 + 0) * N_ + n] = o0;
    out[((size_t)b * 3 + 1) * N_ + n] = o1;
    out[((size_t)b * 3 + 2) * N_ + n] = o2;
}

extern "C" void kernel_launch(void* const* d_in, const int* in_sizes, int n_in,
                              void* d_out, int out_size, void* d_ws, size_t ws_size,
                              hipStream_t stream) {
    const float* coords  = (const float*)d_in[0];
    const float* feats   = (const float*)d_in[1];
    const float* conv_w  = (const float*)d_in[2];
    const float* conv_b  = (const float*)d_in[3];
    const float* wq      = (const float*)d_in[4];
    const float* wk      = (const float*)d_in[5];
    const float* wv      = (const float*)d_in[6];
    const float* wo      = (const float*)d_in[7];
    const float* se_w1   = (const float*)d_in[8];
    const float* se_b1   = (const float*)d_in[9];
    const float* se_w2   = (const float*)d_in[10];
    const float* se_b2   = (const float*)d_in[11];
    const float* point_w = (const float*)d_in[12];
    const float* point_b = (const float*)d_in[13];
    const float* cls_w1  = (const float*)d_in[14];
    const float* cls_b1  = (const float*)d_in[15];
    const float* cls_w2  = (const float*)d_in[16];
    const float* cls_b2  = (const float*)d_in[17];

    float* ws = (float*)d_ws;
    float* vsum   = ws;                    // B*6*S
    float* cnt    = ws + 98304;            // B*S
    float* semean = ws + 114688;           // B*64
    float* gate   = ws + 114944;           // B*64
    float* vox    = ws + 115200;           // B*64*S f32
    float* slotA  = vox + 1048576;         // 4MB: qT + kT (bf16)
    unsigned short* qT = (unsigned short*)slotA;
    unsigned short* kT = qT + 1048576;
    float* vbuf   = slotA + 1048576;       // B*64*S f32
    float* pvT    = vbuf + 1048576;        // B*S*64 f32
    float* xatt   = pvT + 1048576;         // B*64*S f32
    float* xt     = slotA;                 // reuse qT/kT after attention

    hipMemsetAsync(ws, 0, 114944 * sizeof(float), stream);
    k_voxelize<<<512, 256, 0, stream>>>(coords, feats, vsum, cnt);
    k_meandiv<<<384, 256, 0, stream>>>(vsum, cnt);
    k_conv<<<4096, 256, 0, stream>>>(vsum, conv_w, conv_b, vox);
    k_qkv2<<<128, 256, 0, stream>>>(vox, wq, wk, wv, qT, kT, vbuf);
    k_attn_mfma<<<256, 256, 0, stream>>>(qT, kT, vbuf, pvT);
    k_wo<<<64, 256, 0, stream>>>(pvT, wo, vox, xatt);
    k_semean<<<256, 256, 0, stream>>>(xatt, semean);
    k_gate<<<4, 64, 0, stream>>>(semean, se_w1, se_b1, se_w2, se_b2, gate);
    k_transpose2<<<256, 256, 0, stream>>>(xatt, gate, xt);
    k_point<<<512, 256, 0, stream>>>(coords, feats, xt, point_w, point_b,
                                     cls_w1, cls_b1, cls_w2, cls_b2, (float*)d_out);
}

// Round 4
// 394.710 us; speedup vs baseline: 2.4405x; 1.0127x over previous
//
#include <hip/hip_runtime.h>
#include <hip/hip_bf16.h>
#include <math.h>

#define B_ 4
#define N_ 32768
#define CIN 6
#define C_ 64
#define R_ 16
#define S_ 4096

typedef __attribute__((ext_vector_type(8))) __bf16 bf16x8;
typedef __attribute__((ext_vector_type(8))) short short8;
typedef __attribute__((ext_vector_type(4))) float f32x4;

#define MFMA16(a, b, c) __builtin_amdgcn_mfma_f32_16x16x32_bf16((a), (b), (c), 0, 0, 0)

__device__ inline f32x4 zero4() {
    f32x4 z;
    z[0] = 0.f; z[1] = 0.f; z[2] = 0.f; z[3] = 0.f;
    return z;
}

__device__ inline unsigned short f2bf(float f) {
    unsigned u = __builtin_bit_cast(unsigned, f);
    u += 0x7fffu + ((u >> 16) & 1u);          // RNE
    return (unsigned short)(u >> 16);
}

__device__ inline short8 pack8(float4 a, float4 b) {
    short8 r;
    r[0] = (short)f2bf(a.x); r[1] = (short)f2bf(a.y); r[2] = (short)f2bf(a.z); r[3] = (short)f2bf(a.w);
    r[4] = (short)f2bf(b.x); r[5] = (short)f2bf(b.y); r[6] = (short)f2bf(b.z); r[7] = (short)f2bf(b.w);
    return r;
}

// ---------------- K1: voxelize scatter-add ----------------
__global__ void k_voxelize(const float* __restrict__ coords, const float* __restrict__ feats,
                           float* __restrict__ vsum, float* __restrict__ cnt) {
    int idx = blockIdx.x * 256 + threadIdx.x;
    int b = idx >> 15, n = idx & (N_ - 1);
    const float* cb = coords + (size_t)b * 3 * N_;
    float x = cb[n], y = cb[N_ + n], z = cb[2 * N_ + n];
    int vx = min(max((int)floorf(x * R_), 0), R_ - 1);
    int vy = min(max((int)floorf(y * R_), 0), R_ - 1);
    int vz = min(max((int)floorf(z * R_), 0), R_ - 1);
    int cell = (vx * R_ + vy) * R_ + vz;
    float* vs = vsum + (size_t)b * CIN * S_;
    const float* fb = feats + (size_t)b * CIN * N_;
#pragma unroll
    for (int f = 0; f < CIN; f++) atomicAdd(&vs[f * S_ + cell], fb[f * N_ + n]);
    atomicAdd(&cnt[b * S_ + cell], 1.0f);
}

// ---------------- K1b: divide by counts ----------------
__global__ void k_meandiv(float* __restrict__ vsum, const float* __restrict__ cnt) {
    int idx = blockIdx.x * 256 + threadIdx.x;
    int b = idx / (CIN * S_);
    int cell = idx & (S_ - 1);
    float c = cnt[b * S_ + cell];
    vsum[idx] = vsum[idx] / fmaxf(c, 1.0f);
}

// ---------------- K2: 3x3x3 conv + bias + relu -> vox [b][c][s] ----------------
__global__ void k_conv(const float* __restrict__ mean, const float* __restrict__ w,
                       const float* __restrict__ bias, float* __restrict__ outv) {
    __shared__ float wl[CIN * 27];
    int bo = blockIdx.x >> 4;
    int chunk = blockIdx.x & 15;
    int b = bo >> 6, o = bo & 63;
    if (threadIdx.x < CIN * 27) wl[threadIdx.x] = w[o * CIN * 27 + threadIdx.x];
    __syncthreads();
    int cell = chunk * 256 + threadIdx.x;
    int x = cell >> 8, y = (cell >> 4) & 15, z = cell & 15;
    const float* mb = mean + (size_t)b * CIN * S_;
    float acc = bias[o];
#pragma unroll
    for (int dx = 0; dx < 3; dx++) {
        int xx = x + dx - 1;
        if ((unsigned)xx >= (unsigned)R_) continue;
#pragma unroll
        for (int dy = 0; dy < 3; dy++) {
            int yy = y + dy - 1;
            if ((unsigned)yy >= (unsigned)R_) continue;
#pragma unroll
            for (int dz = 0; dz < 3; dz++) {
                int zz = z + dz - 1;
                if ((unsigned)zz >= (unsigned)R_) continue;
                int nc = (xx * 16 + yy) * 16 + zz;
#pragma unroll
                for (int i = 0; i < CIN; i++)
                    acc += wl[i * 27 + dx * 9 + dy * 3 + dz] * mb[i * S_ + nc];
            }
        }
    }
    outv[((size_t)b * 64 + o) * S_ + cell] = fmaxf(acc, 0.0f);
}

// ---------------- K3: qkv -> qT,kT bf16 [b][s][64]; vT bf16 [b][c][t]; voxT f32 [b][s][64] ----------------
__global__ __launch_bounds__(256) void k_qkv3(const float* __restrict__ x, const float* __restrict__ wq,
                                              const float* __restrict__ wk, const float* __restrict__ wv,
                                              unsigned short* __restrict__ qT, unsigned short* __restrict__ kT,
                                              unsigned short* __restrict__ vT, float* __restrict__ voxT) {
    __shared__ float wql[16 * 64], wkl[16 * 64], wvl[16 * 64];
    int bid = blockIdx.x;                 // b(4) x schunk(16) x osplit(4)
    int b = bid >> 6;
    int schunk = (bid >> 2) & 15;
    int o0 = (bid & 3) * 16;
    int tid = threadIdx.x;
    for (int i = tid; i < 1024; i += 256) {
        wql[i] = wq[o0 * 64 + i];
        wkl[i] = wk[o0 * 64 + i];
        wvl[i] = wv[o0 * 64 + i];
    }
    __syncthreads();
    int s = schunk * 256 + tid;
    const float* xb = x + (size_t)b * 64 * S_;
    float xr[64];
#pragma unroll
    for (int c = 0; c < 64; c++) xr[c] = xb[c * S_ + s];
    short8 sq[2], sk[2];
#pragma unroll
    for (int oj = 0; oj < 16; oj++) {
        float aq = 0.f, ak = 0.f, av = 0.f;
#pragma unroll
        for (int c = 0; c < 64; c++) {
            float xv = xr[c];
            aq += wql[oj * 64 + c] * xv;
            ak += wkl[oj * 64 + c] * xv;
            av += wvl[oj * 64 + c] * xv;
        }
        sq[oj >> 3][oj & 7] = (short)f2bf(aq);
        sk[oj >> 3][oj & 7] = (short)f2bf(ak);
        vT[((size_t)b * 64 + o0 + oj) * S_ + s] = f2bf(av);
    }
    unsigned short* qrow = qT + ((size_t)b * S_ + s) * 64 + o0;
    unsigned short* krow = kT + ((size_t)b * S_ + s) * 64 + o0;
    *(short8*)(qrow) = sq[0]; *(short8*)(qrow + 8) = sq[1];
    *(short8*)(krow) = sk[0]; *(short8*)(krow + 8) = sk[1];
    if ((bid & 3) == 0) {
        float* vr = voxT + ((size_t)b * S_ + s) * 64;
#pragma unroll
        for (int i = 0; i < 16; i++)
            *(float4*)(vr + i * 4) = make_float4(xr[i * 4], xr[i * 4 + 1], xr[i * 4 + 2], xr[i * 4 + 3]);
    }
}

// ---------------- K4: flash attention, 1 wave/block, B-frags direct from global ----------------
__global__ __launch_bounds__(64) void k_attn2(const unsigned short* __restrict__ qT,
                                              const unsigned short* __restrict__ kT,
                                              const unsigned short* __restrict__ vT,
                                              float* __restrict__ Opart, float* __restrict__ mlpart) {
    __shared__ unsigned short Ps[16 * 64];
    int bid = blockIdx.x;
    int split = bid & 1;
    int qtile = bid >> 1;                  // 0..1023
    int b = qtile >> 8;
    int sq0 = (qtile & 255) * 16;
    int lane = threadIdx.x;
    int lo = lane & 15, hi = lane >> 4;

    const unsigned short* qb = qT + ((size_t)b * S_ + sq0) * 64;
    bf16x8 qf0 = __builtin_bit_cast(bf16x8, *(const short8*)(qb + lo * 64 + hi * 8));
    bf16x8 qf1 = __builtin_bit_cast(bf16x8, *(const short8*)(qb + lo * 64 + hi * 8 + 32));

    f32x4 O[4];
    float m[4], l[4];
#pragma unroll
    for (int cc = 0; cc < 4; cc++) O[cc] = zero4();
#pragma unroll
    for (int j = 0; j < 4; j++) { m[j] = -1e30f; l[j] = 0.f; }

    const unsigned short* kb = kT + (size_t)b * S_ * 64;
    const unsigned short* vb = vT + (size_t)b * 64 * S_;
    int t0beg = split * 2048, t0end = t0beg + 2048;

    for (int t0 = t0beg; t0 < t0end; t0 += 64) {
        // ---- QK^T: B-frags straight from global kT [t][c] ----
        f32x4 Sacc[4];
#pragma unroll
        for (int ct = 0; ct < 4; ct++) {
            const unsigned short* kr = kb + (size_t)(t0 + ct * 16 + lo) * 64 + hi * 8;
            bf16x8 kf0 = __builtin_bit_cast(bf16x8, *(const short8*)kr);
            bf16x8 kf1 = __builtin_bit_cast(bf16x8, *(const short8*)(kr + 32));
            f32x4 z = zero4();
            z = MFMA16(qf0, kf0, z);
            Sacc[ct] = MFMA16(qf1, kf1, z);
        }
        // ---- online softmax ----
#pragma unroll
        for (int j = 0; j < 4; j++) {
            float tm = fmaxf(fmaxf(Sacc[0][j], Sacc[1][j]), fmaxf(Sacc[2][j], Sacc[3][j]));
            tm *= 0.125f;
            tm = fmaxf(tm, __shfl_xor(tm, 1));
            tm = fmaxf(tm, __shfl_xor(tm, 2));
            tm = fmaxf(tm, __shfl_xor(tm, 4));
            tm = fmaxf(tm, __shfl_xor(tm, 8));
            float mn = fmaxf(m[j], tm);
            float esc = __expf(m[j] - mn);
            m[j] = mn;
            int r = hi * 4 + j;
            int swz = (r & 7) << 4;
            float psum = 0.f;
#pragma unroll
            for (int ct = 0; ct < 4; ct++) {
                float p = __expf(Sacc[ct][j] * 0.125f - mn);
                psum += p;
                int t = ct * 16 + lo;
                *(unsigned short*)((char*)Ps + ((r * 128 + t * 2) ^ swz)) = f2bf(p);
            }
            psum += __shfl_xor(psum, 1);
            psum += __shfl_xor(psum, 2);
            psum += __shfl_xor(psum, 4);
            psum += __shfl_xor(psum, 8);
            l[j] = l[j] * esc + psum;
            O[0][j] *= esc; O[1][j] *= esc; O[2][j] *= esc; O[3][j] *= esc;
        }
        __syncthreads();
        // ---- P A-frags from LDS; V B-frags straight from global vT [c][t] ----
        int swz2 = (lo & 7) << 4;
        bf16x8 pa0 = __builtin_bit_cast(bf16x8, *(const short8*)((char*)Ps + ((lo * 128 + hi * 16) ^ swz2)));
        bf16x8 pa1 = __builtin_bit_cast(bf16x8, *(const short8*)((char*)Ps + ((lo * 128 + hi * 16 + 64) ^ swz2)));
#pragma unroll
        for (int cc = 0; cc < 4; cc++) {
            const unsigned short* vr = vb + (size_t)(cc * 16 + lo) * S_ + t0 + hi * 8;
            bf16x8 vf0 = __builtin_bit_cast(bf16x8, *(const short8*)vr);
            bf16x8 vf1 = __builtin_bit_cast(bf16x8, *(const short8*)(vr + 32));
            O[cc] = MFMA16(pa0, vf0, O[cc]);
            O[cc] = MFMA16(pa1, vf1, O[cc]);
        }
        __syncthreads();
    }

    // ---- write unnormalized partials ----
    float* ob = Opart + ((size_t)(split * B_ + b) * S_ + sq0) * 64;
#pragma unroll
    for (int cc = 0; cc < 4; cc++)
#pragma unroll
        for (int j = 0; j < 4; j++)
            ob[(size_t)(hi * 4 + j) * 64 + cc * 16 + lo] = O[cc][j];
    if (lo == 0) {
        float* mlb = mlpart + ((size_t)(split * B_ + b) * S_ + sq0) * 2;
#pragma unroll
        for (int j = 0; j < 4; j++) {
            mlb[(hi * 4 + j) * 2] = m[j];
            mlb[(hi * 4 + j) * 2 + 1] = l[j];
        }
    }
}

// ---------------- K4b: combine the two KV-split partials -> pvT bf16 [row][64] ----------------
__global__ __launch_bounds__(64) void k_comb(const float* __restrict__ Opart, const float* __restrict__ mlpart,
                                             unsigned short* __restrict__ pvT) {
    int row = blockIdx.x * 64 + threadIdx.x;           // 0..16383
    const float* o1 = Opart + (size_t)row * 64;
    const float* o2 = Opart + ((size_t)B_ * S_ + row) * 64;
    float m1 = mlpart[(size_t)row * 2], l1 = mlpart[(size_t)row * 2 + 1];
    float m2 = mlpart[((size_t)B_ * S_ + row) * 2], l2 = mlpart[((size_t)B_ * S_ + row) * 2 + 1];
    float M = fmaxf(m1, m2);
    float w1 = __expf(m1 - M), w2 = __expf(m2 - M);
    float inv = 1.f / (w1 * l1 + w2 * l2);
    unsigned short* pr = pvT + (size_t)row * 64;
#pragma unroll
    for (int i = 0; i < 8; i++) {
        float4 a0 = *(const float4*)(o1 + i * 8);
        float4 a1 = *(const float4*)(o1 + i * 8 + 4);
        float4 c0 = *(const float4*)(o2 + i * 8);
        float4 c1 = *(const float4*)(o2 + i * 8 + 4);
        float4 r0 = make_float4((w1 * a0.x + w2 * c0.x) * inv, (w1 * a0.y + w2 * c0.y) * inv,
                                (w1 * a0.z + w2 * c0.z) * inv, (w1 * a0.w + w2 * c0.w) * inv);
        float4 r1 = make_float4((w1 * a1.x + w2 * c1.x) * inv, (w1 * a1.y + w2 * c1.y) * inv,
                                (w1 * a1.z + w2 * c1.z) * inv, (w1 * a1.w + w2 * c1.w) * inv);
        *(short8*)(pr + i * 8) = pack8(r0, r1);
    }
}

// ---------------- K5: Wo via MFMA + residual + SE-mean partials -> xattT f32 [row][64] ----------------
__global__ __launch_bounds__(256) void k_wo_mfma(const unsigned short* __restrict__ pvT,
                                                 const float* __restrict__ wo,
                                                 const float* __restrict__ voxT,
                                                 float* __restrict__ xattT,
                                                 float* __restrict__ semean) {
    __shared__ float sem[64];
    int tid = threadIdx.x;
    if (tid < 64) sem[tid] = 0.f;
    __syncthreads();
    int wid = tid >> 6, lane = tid & 63;
    int lo = lane & 15, hi = lane >> 4;
    int r0 = blockIdx.x * 64 + wid * 16;               // global row (b*S + s)
    int bidx = r0 >> 12;

    const unsigned short* ar = pvT + (size_t)(r0 + lo) * 64 + hi * 8;
    bf16x8 a0 = __builtin_bit_cast(bf16x8, *(const short8*)ar);
    bf16x8 a1 = __builtin_bit_cast(bf16x8, *(const short8*)(ar + 32));

    float colsum[4];
#pragma unroll
    for (int cc = 0; cc < 4; cc++) {
        int o = cc * 16 + lo;
        float4 f0 = *(const float4*)(wo + o * 64 + hi * 8);
        float4 f1 = *(const float4*)(wo + o * 64 + hi * 8 + 4);
        bf16x8 b0 = __builtin_bit_cast(bf16x8, pack8(f0, f1));
        float4 f2 = *(const float4*)(wo + o * 64 + 32 + hi * 8);
        float4 f3 = *(const float4*)(wo + o * 64 + 32 + hi * 8 + 4);
        bf16x8 b1 = __builtin_bit_cast(bf16x8, pack8(f2, f3));
        f32x4 acc = zero4();
        acc = MFMA16(a0, b0, acc);
        acc = MFMA16(a1, b1, acc);
        float cs = 0.f;
#pragma unroll
        for (int j = 0; j < 4; j++) {
            size_t idx = (size_t)(r0 + hi * 4 + j) * 64 + o;
            float xn = acc[j] + voxT[idx];
            xattT[idx] = xn;
            cs += xn;
        }
        cs += __shfl_xor(cs, 16);
        cs += __shfl_xor(cs, 32);
        colsum[cc] = cs;
    }
    if (hi == 0) {
#pragma unroll
        for (int cc = 0; cc < 4; cc++) atomicAdd(&sem[cc * 16 + lo], colsum[cc]);
    }
    __syncthreads();
    if (tid < 64) atomicAdd(&semean[bidx * 64 + tid], sem[tid]);
}

// ---------------- K6: SE gate ----------------
__global__ void k_gate(const float* __restrict__ semean, const float* __restrict__ w1,
                       const float* __restrict__ b1, const float* __restrict__ w2,
                       const float* __restrict__ b2, float* __restrict__ gate) {
    __shared__ float sm[64];
    __shared__ float hh[8];
    int b = blockIdx.x, c = threadIdx.x;
    sm[c] = semean[b * 64 + c] * (1.0f / S_);
    __syncthreads();
    if (c < 8) {
        float a = b1[c];
        for (int i = 0; i < 64; i++) a += w1[c * 64 + i] * sm[i];
        hh[c] = fmaxf(a, 0.f);
    }
    __syncthreads();
    float g = b2[c];
#pragma unroll
    for (int j = 0; j < 8; j++) g += w2[c * 8 + j] * hh[j];
    gate[b * 64 + c] = 1.f / (1.f + __expf(-g));
}

// ---------------- K8: devoxelize (+gate) + point MLP + classifier ----------------
__global__ __launch_bounds__(256) void k_point(const float* __restrict__ coords, const float* __restrict__ feats,
                                               const float* __restrict__ xt, const float* __restrict__ gate,
                                               const float* __restrict__ pw,
                                               const float* __restrict__ pb, const float* __restrict__ w1,
                                               const float* __restrict__ b1, const float* __restrict__ w2,
                                               const float* __restrict__ b2, float* __restrict__ out) {
    __shared__ float w1l[128 * 64];
    __shared__ float pwl[64 * 6];
    __shared__ float pbl[64];
    __shared__ float b1l[128];
    __shared__ float w2l[3 * 128];
    __shared__ float b2l[3];
    __shared__ float gl[64];
    int tid = threadIdx.x;
    int gidx = blockIdx.x * 256 + tid;
    int b = gidx >> 15, n = gidx & (N_ - 1);
    for (int i = tid; i < 128 * 64; i += 256) w1l[i] = w1[i];
    for (int i = tid; i < 384; i += 256) { pwl[i] = pw[i]; w2l[i] = w2[i]; }
    if (tid < 128) b1l[tid] = b1[tid];
    if (tid < 64) { pbl[tid] = pb[tid]; gl[tid] = gate[b * 64 + tid]; }
    if (tid < 3) b2l[tid] = b2[tid];
    __syncthreads();
    const float* cb = coords + (size_t)b * 3 * N_;
    float px = fminf(fmaxf(cb[n] * R_ - 0.5f, 0.f), 15.f);
    float py = fminf(fmaxf(cb[N_ + n] * R_ - 0.5f, 0.f), 15.f);
    float pz = fminf(fmaxf(cb[2 * N_ + n] * R_ - 0.5f, 0.f), 15.f);
    int x0 = (int)floorf(px); float wx = px - x0; int x1 = min(x0 + 1, 15);
    int y0 = (int)floorf(py); float wy = py - y0; int y1 = min(y0 + 1, 15);
    int z0 = (int)floorf(pz); float wz = pz - z0; int z1 = min(z0 + 1, 15);
    float fused[64];
#pragma unroll
    for (int c = 0; c < 64; c++) fused[c] = 0.f;
    const float* xb = xt + (size_t)b * S_ * 64;
#pragma unroll
    for (int dx = 0; dx < 2; dx++) {
#pragma unroll
        for (int dy = 0; dy < 2; dy++) {
#pragma unroll
            for (int dz = 0; dz < 2; dz++) {
                int xi = dx ? x1 : x0, yi = dy ? y1 : y0, zi = dz ? z1 : z0;
                float wgt = (dx ? wx : 1.f - wx) * (dy ? wy : 1.f - wy) * (dz ? wz : 1.f - wz);
                const float4* g = (const float4*)(xb + (size_t)((xi * 16 + yi) * 16 + zi) * 64);
#pragma unroll
                for (int c4 = 0; c4 < 16; c4++) {
                    float4 gv = g[c4];
                    fused[c4 * 4 + 0] += wgt * gv.x;
                    fused[c4 * 4 + 1] += wgt * gv.y;
                    fused[c4 * 4 + 2] += wgt * gv.z;
                    fused[c4 * 4 + 3] += wgt * gv.w;
                }
            }
        }
    }
    float fv[6];
#pragma unroll
    for (int i = 0; i < 6; i++) fv[i] = feats[((size_t)b * 6 + i) * N_ + n];
#pragma unroll
    for (int c = 0; c < 64; c++) {
        float pt = pbl[c];
#pragma unroll
        for (int i = 0; i < 6; i++) pt += pwl[c * 6 + i] * fv[i];
        pt = fmaxf(pt, 0.f);
        fused[c] = fmaxf(fused[c] * gl[c] + pt, 0.f);
    }
    float o0 = b2l[0], o1 = b2l[1], o2 = b2l[2];
    for (int j = 0; j < 128; j++) {
        float hj = b1l[j];
#pragma unroll
        for (int c4 = 0; c4 < 16; c4++) {
            float4 wv = *(const float4*)&w1l[j * 64 + c4 * 4];
            hj += wv.x * fused[c4 * 4] + wv.y * fused[c4 * 4 + 1] +
                  wv.z * fused[c4 * 4 + 2] + wv.w * fused[c4 * 4 + 3];
        }
        hj = fmaxf(hj, 0.f);
        o0 += w2l[j] * hj;
        o1 += w2l[128 + j] * hj;
        o2 += w2l[256 + j] * hj;
    }
    out[((size_t)b * 3 + 0) * N_ + n] = o0;
    out[((size_t)b * 3 + 1) * N_ + n] = o1;
    out[((size_t)b * 3 + 2) * N_ + n] = o2;
}

extern "C" void kernel_launch(void* const* d_in, const int* in_sizes, int n_in,
                              void* d_out, int out_size, void* d_ws, size_t ws_size,
                              hipStream_t stream) {
    const float* coords  = (const float*)d_in[0];
    const float* feats   = (const float*)d_in[1];
    const float* conv_w  = (const float*)d_in[2];
    const float* conv_b  = (const float*)d_in[3];
    const float* wq      = (const float*)d_in[4];
    const float* wk      = (const float*)d_in[5];
    const float* wv      = (const float*)d_in[6];
    const float* wo      = (const float*)d_in[7];
    const float* se_w1   = (const float*)d_in[8];
    const float* se_b1   = (const float*)d_in[9];
    const float* se_w2   = (const float*)d_in[10];
    const float* se_b2   = (const float*)d_in[11];
    const float* point_w = (const float*)d_in[12];
    const float* point_b = (const float*)d_in[13];
    const float* cls_w1  = (const float*)d_in[14];
    const float* cls_b1  = (const float*)d_in[15];
    const float* cls_w2  = (const float*)d_in[16];
    const float* cls_b2  = (const float*)d_in[17];

    float* ws = (float*)d_ws;
    float* vsum   = ws;                        // 98304
    float* cnt    = ws + 98304;                // 16384
    float* semean = ws + 114688;               // 256
    float* gate   = ws + 114944;               // 256
    float* vox    = ws + 115200;               // 1048576  [conv -> qkv3]; reused as xattT
    float* voxT   = vox + 1048576;             // 1048576  [qkv3 -> wo]
    unsigned short* qT = (unsigned short*)(voxT + 1048576);   // bf16, 524288 fl
    unsigned short* kT = qT + 1048576;         // bf16, 524288 fl
    unsigned short* vT = kT + 1048576;         // bf16, 524288 fl
    unsigned short* pvT = vT + 1048576;        // bf16, 524288 fl
    float* Opart  = (float*)(pvT + 1048576);   // 2097152
    float* mlpart = Opart + 2097152;           // 65536
    float* xattT  = vox;                       // vox dead after k_qkv3

    hipMemsetAsync(ws, 0, 114944 * sizeof(float), stream);    // vsum + cnt + semean
    k_voxelize<<<512, 256, 0, stream>>>(coords, feats, vsum, cnt);
    k_meandiv<<<384, 256, 0, stream>>>(vsum, cnt);
    k_conv<<<4096, 256, 0, stream>>>(vsum, conv_w, conv_b, vox);
    k_qkv3<<<256, 256, 0, stream>>>(vox, wq, wk, wv, qT, kT, vT, voxT);
    k_attn2<<<2048, 64, 0, stream>>>(qT, kT, vT, Opart, mlpart);
    k_comb<<<256, 64, 0, stream>>>(Opart, mlpart, pvT);
    k_wo_mfma<<<256, 256, 0, stream>>>(pvT, wo, voxT, xattT, semean);
    k_gate<<<4, 64, 0, stream>>>(semean, se_w1, se_b1, se_w2, se_b2, gate);
    k_point<<<512, 256, 0, stream>>>(coords, feats, xattT, gate, point_w, point_b,
                                     cls_w1, cls_b1, cls_w2, cls_b2, (float*)d_out);
}

// Round 5
// 350.695 us; speedup vs baseline: 2.7468x; 1.1255x over previous
//
#include <hip/hip_runtime.h>
#include <hip/hip_bf16.h>
#include <math.h>

#define B_ 4
#define N_ 32768
#define CIN 6
#define C_ 64
#define R_ 16
#define S_ 4096

typedef __attribute__((ext_vector_type(8))) __bf16 bf16x8;
typedef __attribute__((ext_vector_type(8))) short short8;
typedef __attribute__((ext_vector_type(4))) float f32x4;

#define MFMA16(a, b, c) __builtin_amdgcn_mfma_f32_16x16x32_bf16((a), (b), (c), 0, 0, 0)

__device__ inline f32x4 zero4() {
    f32x4 z;
    z[0] = 0.f; z[1] = 0.f; z[2] = 0.f; z[3] = 0.f;
    return z;
}

__device__ inline unsigned short f2bf(float f) {
    unsigned u = __builtin_bit_cast(unsigned, f);
    u += 0x7fffu + ((u >> 16) & 1u);          // RNE
    return (unsigned short)(u >> 16);
}

__device__ inline short8 pack8(float4 a, float4 b) {
    short8 r;
    r[0] = (short)f2bf(a.x); r[1] = (short)f2bf(a.y); r[2] = (short)f2bf(a.z); r[3] = (short)f2bf(a.w);
    r[4] = (short)f2bf(b.x); r[5] = (short)f2bf(b.y); r[6] = (short)f2bf(b.z); r[7] = (short)f2bf(b.w);
    return r;
}

// ---------------- K1: voxelize scatter-add ----------------
__global__ void k_voxelize(const float* __restrict__ coords, const float* __restrict__ feats,
                           float* __restrict__ vsum, float* __restrict__ cnt) {
    int idx = blockIdx.x * 256 + threadIdx.x;
    int b = idx >> 15, n = idx & (N_ - 1);
    const float* cb = coords + (size_t)b * 3 * N_;
    float x = cb[n], y = cb[N_ + n], z = cb[2 * N_ + n];
    int vx = min(max((int)floorf(x * R_), 0), R_ - 1);
    int vy = min(max((int)floorf(y * R_), 0), R_ - 1);
    int vz = min(max((int)floorf(z * R_), 0), R_ - 1);
    int cell = (vx * R_ + vy) * R_ + vz;
    float* vs = vsum + (size_t)b * CIN * S_;
    const float* fb = feats + (size_t)b * CIN * N_;
#pragma unroll
    for (int f = 0; f < CIN; f++) atomicAdd(&vs[f * S_ + cell], fb[f * N_ + n]);
    atomicAdd(&cnt[b * S_ + cell], 1.0f);
}

// ---------------- K1b: divide by counts ----------------
__global__ void k_meandiv(float* __restrict__ vsum, const float* __restrict__ cnt) {
    int idx = blockIdx.x * 256 + threadIdx.x;
    int b = idx / (CIN * S_);
    int cell = idx & (S_ - 1);
    float c = cnt[b * S_ + cell];
    vsum[idx] = vsum[idx] / fmaxf(c, 1.0f);
}

// ---------------- K2: 3x3x3 conv + bias + relu -> vox [b][c][s] ----------------
__global__ void k_conv(const float* __restrict__ mean, const float* __restrict__ w,
                       const float* __restrict__ bias, float* __restrict__ outv) {
    __shared__ float wl[CIN * 27];
    int bo = blockIdx.x >> 4;
    int chunk = blockIdx.x & 15;
    int b = bo >> 6, o = bo & 63;
    if (threadIdx.x < CIN * 27) wl[threadIdx.x] = w[o * CIN * 27 + threadIdx.x];
    __syncthreads();
    int cell = chunk * 256 + threadIdx.x;
    int x = cell >> 8, y = (cell >> 4) & 15, z = cell & 15;
    const float* mb = mean + (size_t)b * CIN * S_;
    float acc = bias[o];
#pragma unroll
    for (int dx = 0; dx < 3; dx++) {
        int xx = x + dx - 1;
        if ((unsigned)xx >= (unsigned)R_) continue;
#pragma unroll
        for (int dy = 0; dy < 3; dy++) {
            int yy = y + dy - 1;
            if ((unsigned)yy >= (unsigned)R_) continue;
#pragma unroll
            for (int dz = 0; dz < 3; dz++) {
                int zz = z + dz - 1;
                if ((unsigned)zz >= (unsigned)R_) continue;
                int nc = (xx * 16 + yy) * 16 + zz;
#pragma unroll
                for (int i = 0; i < CIN; i++)
                    acc += wl[i * 27 + dx * 9 + dy * 3 + dz] * mb[i * S_ + nc];
            }
        }
    }
    outv[((size_t)b * 64 + o) * S_ + cell] = fmaxf(acc, 0.0f);
}

// ---------------- K3: qkv -> qT,kT bf16 [b][s][64]; vT bf16 [b][c][t]; voxT f32 [b][s][64] ----------------
__global__ __launch_bounds__(256) void k_qkv3(const float* __restrict__ x, const float* __restrict__ wq,
                                              const float* __restrict__ wk, const float* __restrict__ wv,
                                              unsigned short* __restrict__ qT, unsigned short* __restrict__ kT,
                                              unsigned short* __restrict__ vT, float* __restrict__ voxT) {
    __shared__ float wql[8 * 64], wkl[8 * 64], wvl[8 * 64];
    int bid = blockIdx.x;                 // b(4) x schunk(16) x osplit(8) = 512
    int b = bid >> 7;
    int schunk = (bid >> 3) & 15;
    int o0 = (bid & 7) * 8;
    int tid = threadIdx.x;
    for (int i = tid; i < 512; i += 256) {
        wql[i] = wq[o0 * 64 + i];
        wkl[i] = wk[o0 * 64 + i];
        wvl[i] = wv[o0 * 64 + i];
    }
    __syncthreads();
    int s = schunk * 256 + tid;
    const float* xb = x + (size_t)b * 64 * S_;
    float xr[64];
#pragma unroll
    for (int c = 0; c < 64; c++) xr[c] = xb[c * S_ + s];
    short8 sq, sk;
#pragma unroll
    for (int oj = 0; oj < 8; oj++) {
        float aq = 0.f, ak = 0.f, av = 0.f;
#pragma unroll
        for (int c = 0; c < 64; c++) {
            float xv = xr[c];
            aq += wql[oj * 64 + c] * xv;
            ak += wkl[oj * 64 + c] * xv;
            av += wvl[oj * 64 + c] * xv;
        }
        sq[oj] = (short)f2bf(aq);
        sk[oj] = (short)f2bf(ak);
        vT[((size_t)b * 64 + o0 + oj) * S_ + s] = f2bf(av);
    }
    *(short8*)(qT + ((size_t)b * S_ + s) * 64 + o0) = sq;
    *(short8*)(kT + ((size_t)b * S_ + s) * 64 + o0) = sk;
    if ((bid & 7) == 0) {
        float* vr = voxT + ((size_t)b * S_ + s) * 64;
#pragma unroll
        for (int i = 0; i < 16; i++)
            *(float4*)(vr + i * 4) = make_float4(xr[i * 4], xr[i * 4 + 1], xr[i * 4 + 2], xr[i * 4 + 3]);
    }
}

// ---------------- K4: flash attention, fixed-max softmax, register-prefetched ----------------
__global__ __launch_bounds__(64) void k_attn3(const unsigned short* __restrict__ qT,
                                              const unsigned short* __restrict__ kT,
                                              const unsigned short* __restrict__ vT,
                                              float* __restrict__ Opart, float* __restrict__ lpart) {
    __shared__ unsigned short Ps[16 * 64];
    int bid = blockIdx.x;
    int split = bid & 1;
    int qtile = bid >> 1;                  // 0..1023
    int b = qtile >> 8;
    int sq0 = (qtile & 255) * 16;
    int lane = threadIdx.x;
    int lo = lane & 15, hi = lane >> 4;

    const unsigned short* qb = qT + ((size_t)b * S_ + sq0) * 64;
    bf16x8 qf0 = __builtin_bit_cast(bf16x8, *(const short8*)(qb + lo * 64 + hi * 8));
    bf16x8 qf1 = __builtin_bit_cast(bf16x8, *(const short8*)(qb + lo * 64 + hi * 8 + 32));

    f32x4 O[4];
    float l[4];
#pragma unroll
    for (int cc = 0; cc < 4; cc++) O[cc] = zero4();
#pragma unroll
    for (int j = 0; j < 4; j++) l[j] = 0.f;

    const unsigned short* kb = kT + (size_t)b * S_ * 64 + hi * 8;
    const unsigned short* vb = vT + (size_t)b * 64 * S_;
    int t0beg = split * 2048;

    short8 ka[8], kn[8];
#pragma unroll
    for (int ct = 0; ct < 4; ct++) {
        const unsigned short* kr = kb + (size_t)(t0beg + ct * 16 + lo) * 64;
        ka[2 * ct] = *(const short8*)kr;
        ka[2 * ct + 1] = *(const short8*)(kr + 32);
    }

    auto body = [&](int t0, short8* kf, short8* knext) {
        // issue V loads for this tile (consumed at the end of the body)
        short8 vf[8];
#pragma unroll
        for (int cc = 0; cc < 4; cc++) {
            const unsigned short* vr = vb + (size_t)(cc * 16 + lo) * S_ + t0 + hi * 8;
            vf[2 * cc] = *(const short8*)vr;
            vf[2 * cc + 1] = *(const short8*)(vr + 32);
        }
        // QK^T
        f32x4 Sacc[4];
#pragma unroll
        for (int ct = 0; ct < 4; ct++) {
            f32x4 z = zero4();
            z = MFMA16(qf0, __builtin_bit_cast(bf16x8, kf[2 * ct]), z);
            Sacc[ct] = MFMA16(qf1, __builtin_bit_cast(bf16x8, kf[2 * ct + 1]), z);
        }
        // prefetch next tile's K frags (reads stay inside workspace; last tile reads junk, unused)
#pragma unroll
        for (int ct = 0; ct < 4; ct++) {
            const unsigned short* kr = kb + (size_t)(t0 + 64 + ct * 16 + lo) * 64;
            knext[2 * ct] = *(const short8*)kr;
            knext[2 * ct + 1] = *(const short8*)(kr + 32);
        }
        // fixed-max softmax: P = exp(S/8); no cross-lane ops in the loop
#pragma unroll
        for (int j = 0; j < 4; j++) {
            int r = hi * 4 + j;
            int swz = (r & 7) << 4;
#pragma unroll
            for (int ct = 0; ct < 4; ct++) {
                float p = __expf(Sacc[ct][j] * 0.125f);
                l[j] += p;
                *(unsigned short*)((char*)Ps + ((r * 128 + (ct * 16 + lo) * 2) ^ swz)) = f2bf(p);
            }
        }
        __syncthreads();
        int swz2 = (lo & 7) << 4;
        bf16x8 pa0 = __builtin_bit_cast(bf16x8, *(const short8*)((char*)Ps + ((lo * 128 + hi * 16) ^ swz2)));
        bf16x8 pa1 = __builtin_bit_cast(bf16x8, *(const short8*)((char*)Ps + ((lo * 128 + hi * 16 + 64) ^ swz2)));
#pragma unroll
        for (int cc = 0; cc < 4; cc++) {
            O[cc] = MFMA16(pa0, __builtin_bit_cast(bf16x8, vf[2 * cc]), O[cc]);
            O[cc] = MFMA16(pa1, __builtin_bit_cast(bf16x8, vf[2 * cc + 1]), O[cc]);
        }
        __syncthreads();
    };

    for (int t0 = t0beg; t0 < t0beg + 2048; t0 += 128) {
        body(t0, ka, kn);
        body(t0 + 64, kn, ka);
    }

    // ---- write unnormalized partials + row sums ----
    float* ob = Opart + ((size_t)(split * B_ + b) * S_ + sq0) * 64;
#pragma unroll
    for (int cc = 0; cc < 4; cc++)
#pragma unroll
        for (int j = 0; j < 4; j++)
            ob[(size_t)(hi * 4 + j) * 64 + cc * 16 + lo] = O[cc][j];
#pragma unroll
    for (int j = 0; j < 4; j++) {
        float s = l[j];
        s += __shfl_xor(s, 1);
        s += __shfl_xor(s, 2);
        s += __shfl_xor(s, 4);
        s += __shfl_xor(s, 8);
        if (lo == 0) lpart[(size_t)(split * B_ + b) * S_ + sq0 + hi * 4 + j] = s;
    }
}

// ---------------- K4b: combine the two KV-split partials -> pvT bf16 [row][64] ----------------
__global__ __launch_bounds__(64) void k_comb(const float* __restrict__ Opart, const float* __restrict__ lpart,
                                             unsigned short* __restrict__ pvT) {
    int row = blockIdx.x * 64 + threadIdx.x;           // 0..16383
    const float* o1 = Opart + (size_t)row * 64;
    const float* o2 = Opart + ((size_t)B_ * S_ + row) * 64;
    float inv = 1.f / (lpart[row] + lpart[B_ * S_ + row]);
    unsigned short* pr = pvT + (size_t)row * 64;
#pragma unroll
    for (int i = 0; i < 8; i++) {
        float4 a0 = *(const float4*)(o1 + i * 8);
        float4 a1 = *(const float4*)(o1 + i * 8 + 4);
        float4 c0 = *(const float4*)(o2 + i * 8);
        float4 c1 = *(const float4*)(o2 + i * 8 + 4);
        float4 r0 = make_float4((a0.x + c0.x) * inv, (a0.y + c0.y) * inv,
                                (a0.z + c0.z) * inv, (a0.w + c0.w) * inv);
        float4 r1 = make_float4((a1.x + c1.x) * inv, (a1.y + c1.y) * inv,
                                (a1.z + c1.z) * inv, (a1.w + c1.w) * inv);
        *(short8*)(pr + i * 8) = pack8(r0, r1);
    }
}

// ---------------- K5: Wo via MFMA + residual + SE-mean partials -> xattT f32 [row][64] ----------------
__global__ __launch_bounds__(256) void k_wo_mfma(const unsigned short* __restrict__ pvT,
                                                 const float* __restrict__ wo,
                                                 const float* __restrict__ voxT,
                                                 float* __restrict__ xattT,
                                                 float* __restrict__ semean) {
    __shared__ float sem[64];
    int tid = threadIdx.x;
    if (tid < 64) sem[tid] = 0.f;
    __syncthreads();
    int wid = tid >> 6, lane = tid & 63;
    int lo = lane & 15, hi = lane >> 4;
    int r0 = blockIdx.x * 64 + wid * 16;               // global row (b*S + s)
    int bidx = r0 >> 12;

    const unsigned short* ar = pvT + (size_t)(r0 + lo) * 64 + hi * 8;
    bf16x8 a0 = __builtin_bit_cast(bf16x8, *(const short8*)ar);
    bf16x8 a1 = __builtin_bit_cast(bf16x8, *(const short8*)(ar + 32));

    float colsum[4];
#pragma unroll
    for (int cc = 0; cc < 4; cc++) {
        int o = cc * 16 + lo;
        float4 f0 = *(const float4*)(wo + o * 64 + hi * 8);
        float4 f1 = *(const float4*)(wo + o * 64 + hi * 8 + 4);
        bf16x8 b0 = __builtin_bit_cast(bf16x8, pack8(f0, f1));
        float4 f2 = *(const float4*)(wo + o * 64 + 32 + hi * 8);
        float4 f3 = *(const float4*)(wo + o * 64 + 32 + hi * 8 + 4);
        bf16x8 b1 = __builtin_bit_cast(bf16x8, pack8(f2, f3));
        f32x4 acc = zero4();
        acc = MFMA16(a0, b0, acc);
        acc = MFMA16(a1, b1, acc);
        float cs = 0.f;
#pragma unroll
        for (int j = 0; j < 4; j++) {
            size_t idx = (size_t)(r0 + hi * 4 + j) * 64 + o;
            float xn = acc[j] + voxT[idx];
            xattT[idx] = xn;
            cs += xn;
        }
        cs += __shfl_xor(cs, 16);
        cs += __shfl_xor(cs, 32);
        colsum[cc] = cs;
    }
    if (hi == 0) {
#pragma unroll
        for (int cc = 0; cc < 4; cc++) atomicAdd(&sem[cc * 16 + lo], colsum[cc]);
    }
    __syncthreads();
    if (tid < 64) atomicAdd(&semean[bidx * 64 + tid], sem[tid]);
}

// ---------------- K6: SE gate ----------------
__global__ void k_gate(const float* __restrict__ semean, const float* __restrict__ w1,
                       const float* __restrict__ b1, const float* __restrict__ w2,
                       const float* __restrict__ b2, float* __restrict__ gate) {
    __shared__ float sm[64];
    __shared__ float hh[8];
    int b = blockIdx.x, c = threadIdx.x;
    sm[c] = semean[b * 64 + c] * (1.0f / S_);
    __syncthreads();
    if (c < 8) {
        float a = b1[c];
        for (int i = 0; i < 64; i++) a += w1[c * 64 + i] * sm[i];
        hh[c] = fmaxf(a, 0.f);
    }
    __syncthreads();
    float g = b2[c];
#pragma unroll
    for (int j = 0; j < 8; j++) g += w2[c * 8 + j] * hh[j];
    gate[b * 64 + c] = 1.f / (1.f + __expf(-g));
}

// ---------------- K8: devoxelize (+gate) + point MLP + classifier ----------------
__global__ __launch_bounds__(256) void k_point(const float* __restrict__ coords, const float* __restrict__ feats,
                                               const float* __restrict__ xt, const float* __restrict__ gate,
                                               const float* __restrict__ pw,
                                               const float* __restrict__ pb, const float* __restrict__ w1,
                                               const float* __restrict__ b1, const float* __restrict__ w2,
                                               const float* __restrict__ b2, float* __restrict__ out) {
    __shared__ float w1l[128 * 64];
    __shared__ float pwl[64 * 6];
    __shared__ float pbl[64];
    __shared__ float b1l[128];
    __shared__ float w2l[3 * 128];
    __shared__ float b2l[3];
    __shared__ float gl[64];
    int tid = threadIdx.x;
    int gidx = blockIdx.x * 256 + tid;
    int b = gidx >> 15, n = gidx & (N_ - 1);
    for (int i = tid; i < 128 * 64; i += 256) w1l[i] = w1[i];
    for (int i = tid; i < 384; i += 256) { pwl[i] = pw[i]; w2l[i] = w2[i]; }
    if (tid < 128) b1l[tid] = b1[tid];
    if (tid < 64) { pbl[tid] = pb[tid]; gl[tid] = gate[b * 64 + tid]; }
    if (tid < 3) b2l[tid] = b2[tid];
    __syncthreads();
    const float* cb = coords + (size_t)b * 3 * N_;
    float px = fminf(fmaxf(cb[n] * R_ - 0.5f, 0.f), 15.f);
    float py = fminf(fmaxf(cb[N_ + n] * R_ - 0.5f, 0.f), 15.f);
    float pz = fminf(fmaxf(cb[2 * N_ + n] * R_ - 0.5f, 0.f), 15.f);
    int x0 = (int)floorf(px); float wx = px - x0; int x1 = min(x0 + 1, 15);
    int y0 = (int)floorf(py); float wy = py - y0; int y1 = min(y0 + 1, 15);
    int z0 = (int)floorf(pz); float wz = pz - z0; int z1 = min(z0 + 1, 15);
    float fused[64];
#pragma unroll
    for (int c = 0; c < 64; c++) fused[c] = 0.f;
    const float* xb = xt + (size_t)b * S_ * 64;
#pragma unroll
    for (int dx = 0; dx < 2; dx++) {
#pragma unroll
        for (int dy = 0; dy < 2; dy++) {
#pragma unroll
            for (int dz = 0; dz < 2; dz++) {
                int xi = dx ? x1 : x0, yi = dy ? y1 : y0, zi = dz ? z1 : z0;
                float wgt = (dx ? wx : 1.f - wx) * (dy ? wy : 1.f - wy) * (dz ? wz : 1.f - wz);
                const float4* g = (const float4*)(xb + (size_t)((xi * 16 + yi) * 16 + zi) * 64);
#pragma unroll
                for (int c4 = 0; c4 < 16; c4++) {
                    float4 gv = g[c4];
                    fused[c4 * 4 + 0] += wgt * gv.x;
                    fused[c4 * 4 + 1] += wgt * gv.y;
                    fused[c4 * 4 + 2] += wgt * gv.z;
                    fused[c4 * 4 + 3] += wgt * gv.w;
                }
            }
        }
    }
    float fv[6];
#pragma unroll
    for (int i = 0; i < 6; i++) fv[i] = feats[((size_t)b * 6 + i) * N_ + n];
#pragma unroll
    for (int c = 0; c < 64; c++) {
        float pt = pbl[c];
#pragma unroll
        for (int i = 0; i < 6; i++) pt += pwl[c * 6 + i] * fv[i];
        pt = fmaxf(pt, 0.f);
        fused[c] = fmaxf(fused[c] * gl[c] + pt, 0.f);
    }
    float o0 = b2l[0], o1 = b2l[1], o2 = b2l[2];
    for (int j = 0; j < 128; j++) {
        float hj = b1l[j];
#pragma unroll
        for (int c4 = 0; c4 < 16; c4++) {
            float4 wv = *(const float4*)&w1l[j * 64 + c4 * 4];
            hj += wv.x * fused[c4 * 4] + wv.y * fused[c4 * 4 + 1] +
                  wv.z * fused[c4 * 4 + 2] + wv.w * fused[c4 * 4 + 3];
        }
        hj = fmaxf(hj, 0.f);
        o0 += w2l[j] * hj;
        o1 += w2l[128 + j] * hj;
        o2 += w2l[256 + j] * hj;
    }
    out[((size_t)b * 3 + 0) * N_ + n] = o0;
    out[((size_t)b * 3 + 1) * N_ + n] = o1;
    out[((size_t)b * 3 + 2) * N_ + n] = o2;
}

extern "C" void kernel_launch(void* const* d_in, const int* in_sizes, int n_in,
                              void* d_out, int out_size, void* d_ws, size_t ws_size,
                              hipStream_t stream) {
    const float* coords  = (const float*)d_in[0];
    const float* feats   = (const float*)d_in[1];
    const float* conv_w  = (const float*)d_in[2];
    const float* conv_b  = (const float*)d_in[3];
    const float* wq      = (const float*)d_in[4];
    const float* wk      = (const float*)d_in[5];
    const float* wv      = (const float*)d_in[6];
    const float* wo      = (const float*)d_in[7];
    const float* se_w1   = (const float*)d_in[8];
    const float* se_b1   = (const float*)d_in[9];
    const float* se_w2   = (const float*)d_in[10];
    const float* se_b2   = (const float*)d_in[11];
    const float* point_w = (const float*)d_in[12];
    const float* point_b = (const float*)d_in[13];
    const float* cls_w1  = (const float*)d_in[14];
    const float* cls_b1  = (const float*)d_in[15];
    const float* cls_w2  = (const float*)d_in[16];
    const float* cls_b2  = (const float*)d_in[17];

    float* ws = (float*)d_ws;
    float* vsum   = ws;                        // 98304
    float* cnt    = ws + 98304;                // 16384
    float* semean = ws + 114688;               // 256
    float* gate   = ws + 114944;               // 256
    float* vox    = ws + 115200;               // 1048576  [conv -> qkv3]; reused as xattT
    float* voxT   = vox + 1048576;             // 1048576  [qkv3 -> wo]
    unsigned short* qT = (unsigned short*)(voxT + 1048576);   // bf16, 524288 fl
    unsigned short* kT = qT + 1048576;         // bf16, 524288 fl
    unsigned short* vT = kT + 1048576;         // bf16, 524288 fl
    unsigned short* pvT = vT + 1048576;        // bf16, 524288 fl
    float* Opart  = (float*)(pvT + 1048576);   // 2097152
    float* lpart  = Opart + 2097152;           // 32768
    float* xattT  = vox;                       // vox dead after k_qkv3

    hipMemsetAsync(ws, 0, 114944 * sizeof(float), stream);    // vsum + cnt + semean
    k_voxelize<<<512, 256, 0, stream>>>(coords, feats, vsum, cnt);
    k_meandiv<<<384, 256, 0, stream>>>(vsum, cnt);
    k_conv<<<4096, 256, 0, stream>>>(vsum, conv_w, conv_b, vox);
    k_qkv3<<<512, 256, 0, stream>>>(vox, wq, wk, wv, qT, kT, vT, voxT);
    k_attn3<<<2048, 64, 0, stream>>>(qT, kT, vT, Opart, lpart);
    k_comb<<<256, 64, 0, stream>>>(Opart, lpart, pvT);
    k_wo_mfma<<<256, 256, 0, stream>>>(pvT, wo, voxT, xattT, semean);
    k_gate<<<4, 64, 0, stream>>>(semean, se_w1, se_b1, se_w2, se_b2, gate);
    k_point<<<512, 256, 0, stream>>>(coords, feats, xattT, gate, point_w, point_b,
                                     cls_w1, cls_b1, cls_w2, cls_b2, (float*)d_out);
}

// Round 6
// 347.182 us; speedup vs baseline: 2.7746x; 1.0101x over previous
//
#include <hip/hip_runtime.h>
#include <hip/hip_bf16.h>
#include <math.h>

#define B_ 4
#define N_ 32768
#define CIN 6
#define C_ 64
#define R_ 16
#define S_ 4096

typedef __attribute__((ext_vector_type(8))) __bf16 bf16x8;
typedef __attribute__((ext_vector_type(8))) short short8;
typedef __attribute__((ext_vector_type(4))) float f32x4;

#define MFMA16(a, b, c) __builtin_amdgcn_mfma_f32_16x16x32_bf16((a), (b), (c), 0, 0, 0)

__device__ inline f32x4 zero4() {
    f32x4 z;
    z[0] = 0.f; z[1] = 0.f; z[2] = 0.f; z[3] = 0.f;
    return z;
}

__device__ inline unsigned short f2bf(float f) {
    unsigned u = __builtin_bit_cast(unsigned, f);
    u += 0x7fffu + ((u >> 16) & 1u);          // RNE
    return (unsigned short)(u >> 16);
}

__device__ inline short8 pack8(float4 a, float4 b) {
    short8 r;
    r[0] = (short)f2bf(a.x); r[1] = (short)f2bf(a.y); r[2] = (short)f2bf(a.z); r[3] = (short)f2bf(a.w);
    r[4] = (short)f2bf(b.x); r[5] = (short)f2bf(b.y); r[6] = (short)f2bf(b.z); r[7] = (short)f2bf(b.w);
    return r;
}

// ---------------- K1: voxelize scatter-add ----------------
__global__ void k_voxelize(const float* __restrict__ coords, const float* __restrict__ feats,
                           float* __restrict__ vsum, float* __restrict__ cnt) {
    int idx = blockIdx.x * 256 + threadIdx.x;
    int b = idx >> 15, n = idx & (N_ - 1);
    const float* cb = coords + (size_t)b * 3 * N_;
    float x = cb[n], y = cb[N_ + n], z = cb[2 * N_ + n];
    int vx = min(max((int)floorf(x * R_), 0), R_ - 1);
    int vy = min(max((int)floorf(y * R_), 0), R_ - 1);
    int vz = min(max((int)floorf(z * R_), 0), R_ - 1);
    int cell = (vx * R_ + vy) * R_ + vz;
    float* vs = vsum + (size_t)b * CIN * S_;
    const float* fb = feats + (size_t)b * CIN * N_;
#pragma unroll
    for (int f = 0; f < CIN; f++) atomicAdd(&vs[f * S_ + cell], fb[f * N_ + n]);
    atomicAdd(&cnt[b * S_ + cell], 1.0f);
}

// ---------------- K1b: divide by counts ----------------
__global__ void k_meandiv(float* __restrict__ vsum, const float* __restrict__ cnt) {
    int idx = blockIdx.x * 256 + threadIdx.x;
    int b = idx / (CIN * S_);
    int cell = idx & (S_ - 1);
    float c = cnt[b * S_ + cell];
    vsum[idx] = vsum[idx] / fmaxf(c, 1.0f);
}

// ---------------- K2: 3x3x3 conv + bias + relu -> vox [b][c][s] ----------------
__global__ void k_conv(const float* __restrict__ mean, const float* __restrict__ w,
                       const float* __restrict__ bias, float* __restrict__ outv) {
    __shared__ float wl[CIN * 27];
    int bo = blockIdx.x >> 4;
    int chunk = blockIdx.x & 15;
    int b = bo >> 6, o = bo & 63;
    if (threadIdx.x < CIN * 27) wl[threadIdx.x] = w[o * CIN * 27 + threadIdx.x];
    __syncthreads();
    int cell = chunk * 256 + threadIdx.x;
    int x = cell >> 8, y = (cell >> 4) & 15, z = cell & 15;
    const float* mb = mean + (size_t)b * CIN * S_;
    float acc = bias[o];
#pragma unroll
    for (int dx = 0; dx < 3; dx++) {
        int xx = x + dx - 1;
        if ((unsigned)xx >= (unsigned)R_) continue;
#pragma unroll
        for (int dy = 0; dy < 3; dy++) {
            int yy = y + dy - 1;
            if ((unsigned)yy >= (unsigned)R_) continue;
#pragma unroll
            for (int dz = 0; dz < 3; dz++) {
                int zz = z + dz - 1;
                if ((unsigned)zz >= (unsigned)R_) continue;
                int nc = (xx * 16 + yy) * 16 + zz;
#pragma unroll
                for (int i = 0; i < CIN; i++)
                    acc += wl[i * 27 + dx * 9 + dy * 3 + dz] * mb[i * S_ + nc];
            }
        }
    }
    outv[((size_t)b * 64 + o) * S_ + cell] = fmaxf(acc, 0.0f);
}

// ---------------- K3: qkv -> qT,kT bf16 [b][s][64]; vT bf16 [b][c][t]; voxT f32 [b][s][64] ----------------
__global__ __launch_bounds__(256) void k_qkv3(const float* __restrict__ x, const float* __restrict__ wq,
                                              const float* __restrict__ wk, const float* __restrict__ wv,
                                              unsigned short* __restrict__ qT, unsigned short* __restrict__ kT,
                                              unsigned short* __restrict__ vT, float* __restrict__ voxT) {
    __shared__ float wql[8 * 64], wkl[8 * 64], wvl[8 * 64];
    int bid = blockIdx.x;                 // b(4) x schunk(16) x osplit(8) = 512
    int b = bid >> 7;
    int schunk = (bid >> 3) & 15;
    int o0 = (bid & 7) * 8;
    int tid = threadIdx.x;
    for (int i = tid; i < 512; i += 256) {
        wql[i] = wq[o0 * 64 + i];
        wkl[i] = wk[o0 * 64 + i];
        wvl[i] = wv[o0 * 64 + i];
    }
    __syncthreads();
    int s = schunk * 256 + tid;
    const float* xb = x + (size_t)b * 64 * S_;
    float xr[64];
#pragma unroll
    for (int c = 0; c < 64; c++) xr[c] = xb[c * S_ + s];
    short8 sq, sk;
#pragma unroll
    for (int oj = 0; oj < 8; oj++) {
        float aq = 0.f, ak = 0.f, av = 0.f;
#pragma unroll
        for (int c = 0; c < 64; c++) {
            float xv = xr[c];
            aq += wql[oj * 64 + c] * xv;
            ak += wkl[oj * 64 + c] * xv;
            av += wvl[oj * 64 + c] * xv;
        }
        sq[oj] = (short)f2bf(aq);
        sk[oj] = (short)f2bf(ak);
        vT[((size_t)b * 64 + o0 + oj) * S_ + s] = f2bf(av);
    }
    *(short8*)(qT + ((size_t)b * S_ + s) * 64 + o0) = sq;
    *(short8*)(kT + ((size_t)b * S_ + s) * 64 + o0) = sk;
    if ((bid & 7) == 0) {
        float* vr = voxT + ((size_t)b * S_ + s) * 64;
#pragma unroll
        for (int i = 0; i < 16; i++)
            *(float4*)(vr + i * 4) = make_float4(xr[i * 4], xr[i * 4 + 1], xr[i * 4 + 2], xr[i * 4 + 3]);
    }
}

// ---------------- K4: flash attention, flat loop, no spill, split=4 ----------------
__global__ __launch_bounds__(64, 4) void k_attn4(const unsigned short* __restrict__ qT,
                                                 const unsigned short* __restrict__ kT,
                                                 const unsigned short* __restrict__ vT,
                                                 float* __restrict__ Opart, float* __restrict__ lpart) {
    __shared__ unsigned short Ps[16 * 64];
    int bid = blockIdx.x;                  // qtile(1024) x split(4)
    int split = bid & 3;
    int qtile = bid >> 2;
    int b = qtile >> 8;
    int sq0 = (qtile & 255) * 16;
    int lane = threadIdx.x;
    int lo = lane & 15, hi = lane >> 4;

    const unsigned short* qb = qT + ((size_t)b * S_ + sq0) * 64;
    bf16x8 qf0 = __builtin_bit_cast(bf16x8, *(const short8*)(qb + lo * 64 + hi * 8));
    bf16x8 qf1 = __builtin_bit_cast(bf16x8, *(const short8*)(qb + lo * 64 + hi * 8 + 32));

    f32x4 O[4];
    float l[4];
#pragma unroll
    for (int cc = 0; cc < 4; cc++) O[cc] = zero4();
#pragma unroll
    for (int j = 0; j < 4; j++) l[j] = 0.f;

    const unsigned short* kb = kT + (size_t)b * S_ * 64 + hi * 8;
    const unsigned short* vb = vT + (size_t)b * 64 * S_;

    for (int t0 = split * 1024; t0 < split * 1024 + 1024; t0 += 64) {
        // ---- K frags from global, consumed immediately (regs freed before V) ----
        f32x4 Sacc[4];
#pragma unroll
        for (int ct = 0; ct < 4; ct++) {
            const unsigned short* kr = kb + (size_t)(t0 + ct * 16 + lo) * 64;
            bf16x8 kf0 = __builtin_bit_cast(bf16x8, *(const short8*)kr);
            bf16x8 kf1 = __builtin_bit_cast(bf16x8, *(const short8*)(kr + 32));
            f32x4 z = zero4();
            z = MFMA16(qf0, kf0, z);
            Sacc[ct] = MFMA16(qf1, kf1, z);
        }
        // ---- fixed-max softmax: P = exp(S/8), lane-local l accumulation ----
#pragma unroll
        for (int j = 0; j < 4; j++) {
            int r = hi * 4 + j;
            int swz = (r & 7) << 4;
#pragma unroll
            for (int ct = 0; ct < 4; ct++) {
                float p = __expf(Sacc[ct][j] * 0.125f);
                l[j] += p;
                *(unsigned short*)((char*)Ps + ((r * 128 + (ct * 16 + lo) * 2) ^ swz)) = f2bf(p);
            }
        }
        __syncthreads();
        int swz2 = (lo & 7) << 4;
        bf16x8 pa0 = __builtin_bit_cast(bf16x8, *(const short8*)((char*)Ps + ((lo * 128 + hi * 16) ^ swz2)));
        bf16x8 pa1 = __builtin_bit_cast(bf16x8, *(const short8*)((char*)Ps + ((lo * 128 + hi * 16 + 64) ^ swz2)));
        // ---- V frags from global (reuse K's registers), PV ----
#pragma unroll
        for (int cc = 0; cc < 4; cc++) {
            const unsigned short* vr = vb + (size_t)(cc * 16 + lo) * S_ + t0 + hi * 8;
            bf16x8 vf0 = __builtin_bit_cast(bf16x8, *(const short8*)vr);
            bf16x8 vf1 = __builtin_bit_cast(bf16x8, *(const short8*)(vr + 32));
            O[cc] = MFMA16(pa0, vf0, O[cc]);
            O[cc] = MFMA16(pa1, vf1, O[cc]);
        }
        __syncthreads();
    }

    // ---- write unnormalized partials + row sums ----
    float* ob = Opart + ((size_t)split * B_ * S_ + (size_t)b * S_ + sq0) * 64;
#pragma unroll
    for (int cc = 0; cc < 4; cc++)
#pragma unroll
        for (int j = 0; j < 4; j++)
            ob[(size_t)(hi * 4 + j) * 64 + cc * 16 + lo] = O[cc][j];
#pragma unroll
    for (int j = 0; j < 4; j++) {
        float s = l[j];
        s += __shfl_xor(s, 1);
        s += __shfl_xor(s, 2);
        s += __shfl_xor(s, 4);
        s += __shfl_xor(s, 8);
        if (lo == 0) lpart[(size_t)split * B_ * S_ + (size_t)b * S_ + sq0 + hi * 4 + j] = s;
    }
}

// ---------------- K5: combine(4 splits) + Wo MFMA + residual + SE-mean -> xattT ----------------
__global__ __launch_bounds__(256) void k_wo_mfma(const float* __restrict__ Opart,
                                                 const float* __restrict__ lpart,
                                                 const float* __restrict__ wo,
                                                 const float* __restrict__ voxT,
                                                 float* __restrict__ xattT,
                                                 float* __restrict__ semean) {
    __shared__ float sem[64];
    int tid = threadIdx.x;
    if (tid < 64) sem[tid] = 0.f;
    __syncthreads();
    int wid = tid >> 6, lane = tid & 63;
    int lo = lane & 15, hi = lane >> 4;
    int r0 = blockIdx.x * 64 + wid * 16;               // global row (b*S + s)
    int bidx = r0 >> 12;
    int row = r0 + lo;
    const int BS = B_ * S_;

    // combine the 4 KV-split partials in-register -> A fragment
    float L = lpart[row] + lpart[BS + row] + lpart[2 * BS + row] + lpart[3 * BS + row];
    float inv = 1.f / L;
    float4 q0 = make_float4(0.f, 0.f, 0.f, 0.f), q1 = q0, q2 = q0, q3 = q0;
#pragma unroll
    for (int sp = 0; sp < 4; sp++) {
        const float* orow = Opart + ((size_t)sp * BS + row) * 64 + hi * 8;
        float4 t0 = *(const float4*)(orow);
        float4 t1 = *(const float4*)(orow + 4);
        float4 t2 = *(const float4*)(orow + 32);
        float4 t3 = *(const float4*)(orow + 36);
        q0.x += t0.x; q0.y += t0.y; q0.z += t0.z; q0.w += t0.w;
        q1.x += t1.x; q1.y += t1.y; q1.z += t1.z; q1.w += t1.w;
        q2.x += t2.x; q2.y += t2.y; q2.z += t2.z; q2.w += t2.w;
        q3.x += t3.x; q3.y += t3.y; q3.z += t3.z; q3.w += t3.w;
    }
    q0.x *= inv; q0.y *= inv; q0.z *= inv; q0.w *= inv;
    q1.x *= inv; q1.y *= inv; q1.z *= inv; q1.w *= inv;
    q2.x *= inv; q2.y *= inv; q2.z *= inv; q2.w *= inv;
    q3.x *= inv; q3.y *= inv; q3.z *= inv; q3.w *= inv;
    bf16x8 a0 = __builtin_bit_cast(bf16x8, pack8(q0, q1));
    bf16x8 a1 = __builtin_bit_cast(bf16x8, pack8(q2, q3));

    float colsum[4];
#pragma unroll
    for (int cc = 0; cc < 4; cc++) {
        int o = cc * 16 + lo;
        float4 f0 = *(const float4*)(wo + o * 64 + hi * 8);
        float4 f1 = *(const float4*)(wo + o * 64 + hi * 8 + 4);
        bf16x8 b0 = __builtin_bit_cast(bf16x8, pack8(f0, f1));
        float4 f2 = *(const float4*)(wo + o * 64 + 32 + hi * 8);
        float4 f3 = *(const float4*)(wo + o * 64 + 32 + hi * 8 + 4);
        bf16x8 b1 = __builtin_bit_cast(bf16x8, pack8(f2, f3));
        f32x4 acc = zero4();
        acc = MFMA16(a0, b0, acc);
        acc = MFMA16(a1, b1, acc);
        float cs = 0.f;
#pragma unroll
        for (int j = 0; j < 4; j++) {
            size_t idx = (size_t)(r0 + hi * 4 + j) * 64 + o;
            float xn = acc[j] + voxT[idx];
            xattT[idx] = xn;
            cs += xn;
        }
        cs += __shfl_xor(cs, 16);
        cs += __shfl_xor(cs, 32);
        colsum[cc] = cs;
    }
    if (hi == 0) {
#pragma unroll
        for (int cc = 0; cc < 4; cc++) atomicAdd(&sem[cc * 16 + lo], colsum[cc]);
    }
    __syncthreads();
    if (tid < 64) atomicAdd(&semean[bidx * 64 + tid], sem[tid]);
}

// ---------------- K8: SE gate (recomputed) + devoxelize + point MLP + classifier ----------------
__global__ __launch_bounds__(256) void k_point(const float* __restrict__ coords, const float* __restrict__ feats,
                                               const float* __restrict__ xt, const float* __restrict__ semean,
                                               const float* __restrict__ sw1, const float* __restrict__ sb1,
                                               const float* __restrict__ sw2, const float* __restrict__ sb2,
                                               const float* __restrict__ pw,
                                               const float* __restrict__ pb, const float* __restrict__ w1,
                                               const float* __restrict__ b1, const float* __restrict__ w2,
                                               const float* __restrict__ b2, float* __restrict__ out) {
    __shared__ float w1l[128 * 64];
    __shared__ float pwl[64 * 6];
    __shared__ float pbl[64];
    __shared__ float b1l[128];
    __shared__ float w2l[3 * 128];
    __shared__ float b2l[3];
    __shared__ float gl[64];
    __shared__ float sml[64];
    __shared__ float hh[8];
    int tid = threadIdx.x;
    int gidx = blockIdx.x * 256 + tid;
    int b = gidx >> 15, n = gidx & (N_ - 1);
    for (int i = tid; i < 128 * 64; i += 256) w1l[i] = w1[i];
    for (int i = tid; i < 384; i += 256) { pwl[i] = pw[i]; w2l[i] = w2[i]; }
    if (tid < 128) b1l[tid] = b1[tid];
    if (tid < 64) { pbl[tid] = pb[tid]; sml[tid] = semean[b * 64 + tid] * (1.0f / S_); }
    if (tid < 3) b2l[tid] = b2[tid];
    __syncthreads();
    // SE gate (tiny MLP recomputed per block; kills a kernel launch)
    if (tid < 8) {
        float a = sb1[tid];
#pragma unroll
        for (int i = 0; i < 64; i++) a += sw1[tid * 64 + i] * sml[i];
        hh[tid] = fmaxf(a, 0.f);
    }
    __syncthreads();
    if (tid < 64) {
        float g = sb2[tid];
#pragma unroll
        for (int j = 0; j < 8; j++) g += sw2[tid * 8 + j] * hh[j];
        gl[tid] = 1.f / (1.f + __expf(-g));
    }
    __syncthreads();
    const float* cb = coords + (size_t)b * 3 * N_;
    float px = fminf(fmaxf(cb[n] * R_ - 0.5f, 0.f), 15.f);
    float py = fminf(fmaxf(cb[N_ + n] * R_ - 0.5f, 0.f), 15.f);
    float pz = fminf(fmaxf(cb[2 * N_ + n] * R_ - 0.5f, 0.f), 15.f);
    int x0 = (int)floorf(px); float wx = px - x0; int x1 = min(x0 + 1, 15);
    int y0 = (int)floorf(py); float wy = py - y0; int y1 = min(y0 + 1, 15);
    int z0 = (int)floorf(pz); float wz = pz - z0; int z1 = min(z0 + 1, 15);
    float fused[64];
#pragma unroll
    for (int c = 0; c < 64; c++) fused[c] = 0.f;
    const float* xb = xt + (size_t)b * S_ * 64;
#pragma unroll
    for (int dx = 0; dx < 2; dx++) {
#pragma unroll
        for (int dy = 0; dy < 2; dy++) {
#pragma unroll
            for (int dz = 0; dz < 2; dz++) {
                int xi = dx ? x1 : x0, yi = dy ? y1 : y0, zi = dz ? z1 : z0;
                float wgt = (dx ? wx : 1.f - wx) * (dy ? wy : 1.f - wy) * (dz ? wz : 1.f - wz);
                const float4* g = (const float4*)(xb + (size_t)((xi * 16 + yi) * 16 + zi) * 64);
#pragma unroll
                for (int c4 = 0; c4 < 16; c4++) {
                    float4 gv = g[c4];
                    fused[c4 * 4 + 0] += wgt * gv.x;
                    fused[c4 * 4 + 1] += wgt * gv.y;
                    fused[c4 * 4 + 2] += wgt * gv.z;
                    fused[c4 * 4 + 3] += wgt * gv.w;
                }
            }
        }
    }
    float fv[6];
#pragma unroll
    for (int i = 0; i < 6; i++) fv[i] = feats[((size_t)b * 6 + i) * N_ + n];
#pragma unroll
    for (int c = 0; c < 64; c++) {
        float pt = pbl[c];
#pragma unroll
        for (int i = 0; i < 6; i++) pt += pwl[c * 6 + i] * fv[i];
        pt = fmaxf(pt, 0.f);
        fused[c] = fmaxf(fused[c] * gl[c] + pt, 0.f);
    }
    float o0 = b2l[0], o1 = b2l[1], o2 = b2l[2];
    for (int j = 0; j < 128; j++) {
        float hj = b1l[j];
#pragma unroll
        for (int c4 = 0; c4 < 16; c4++) {
            float4 wv = *(const float4*)&w1l[j * 64 + c4 * 4];
            hj += wv.x * fused[c4 * 4] + wv.y * fused[c4 * 4 + 1] +
                  wv.z * fused[c4 * 4 + 2] + wv.w * fused[c4 * 4 + 3];
        }
        hj = fmaxf(hj, 0.f);
        o0 += w2l[j] * hj;
        o1 += w2l[128 + j] * hj;
        o2 += w2l[256 + j] * hj;
    }
    out[((size_t)b * 3 + 0) * N_ + n] = o0;
    out[((size_t)b * 3 + 1) * N_ + n] = o1;
    out[((size_t)b * 3 + 2) * N_ + n] = o2;
}

extern "C" void kernel_launch(void* const* d_in, const int* in_sizes, int n_in,
                              void* d_out, int out_size, void* d_ws, size_t ws_size,
                              hipStream_t stream) {
    const float* coords  = (const float*)d_in[0];
    const float* feats   = (const float*)d_in[1];
    const float* conv_w  = (const float*)d_in[2];
    const float* conv_b  = (const float*)d_in[3];
    const float* wq      = (const float*)d_in[4];
    const float* wk      = (const float*)d_in[5];
    const float* wv      = (const float*)d_in[6];
    const float* wo      = (const float*)d_in[7];
    const float* se_w1   = (const float*)d_in[8];
    const float* se_b1   = (const float*)d_in[9];
    const float* se_w2   = (const float*)d_in[10];
    const float* se_b2   = (const float*)d_in[11];
    const float* point_w = (const float*)d_in[12];
    const float* point_b = (const float*)d_in[13];
    const float* cls_w1  = (const float*)d_in[14];
    const float* cls_b1  = (const float*)d_in[15];
    const float* cls_w2  = (const float*)d_in[16];
    const float* cls_b2  = (const float*)d_in[17];

    float* ws = (float*)d_ws;
    float* vsum   = ws;                        // 98304
    float* cnt    = ws + 98304;                // 16384
    float* semean = ws + 114688;               // 256
    float* vox    = ws + 115200;               // 1048576  [conv -> qkv3]; reused as xattT
    float* voxT   = vox + 1048576;             // 1048576  [qkv3 -> wo]
    unsigned short* qT = (unsigned short*)(voxT + 1048576);   // bf16, 524288 fl
    unsigned short* kT = qT + 1048576;         // bf16, 524288 fl
    unsigned short* vT = kT + 1048576;         // bf16, 524288 fl
    float* Opart  = (float*)(vT + 1048576);    // 4 splits x 16384 rows x 64 = 4194304
    float* lpart  = Opart + 4194304;           // 65536
    float* xattT  = vox;                       // vox dead after k_qkv3

    hipMemsetAsync(ws, 0, 114944 * sizeof(float), stream);    // vsum + cnt + semean
    k_voxelize<<<512, 256, 0, stream>>>(coords, feats, vsum, cnt);
    k_meandiv<<<384, 256, 0, stream>>>(vsum, cnt);
    k_conv<<<4096, 256, 0, stream>>>(vsum, conv_w, conv_b, vox);
    k_qkv3<<<512, 256, 0, stream>>>(vox, wq, wk, wv, qT, kT, vT, voxT);
    k_attn4<<<4096, 64, 0, stream>>>(qT, kT, vT, Opart, lpart);
    k_wo_mfma<<<256, 256, 0, stream>>>(Opart, lpart, wo, voxT, xattT, semean);
    k_point<<<512, 256, 0, stream>>>(coords, feats, xattT, semean,
                                     se_w1, se_b1, se_w2, se_b2, point_w, point_b,
                                     cls_w1, cls_b1, cls_w2, cls_b2, (float*)d_out);
}

// Round 7
// 299.381 us; speedup vs baseline: 3.2176x; 1.1597x over previous
//
#include <hip/hip_runtime.h>
#include <hip/hip_bf16.h>
#include <math.h>

#define B_ 4
#define N_ 32768
#define CIN 6
#define C_ 64
#define R_ 16
#define S_ 4096

typedef __attribute__((ext_vector_type(8))) __bf16 bf16x8;
typedef __attribute__((ext_vector_type(8))) short short8;
typedef __attribute__((ext_vector_type(4))) float f32x4;

#define MFMA16(a, b, c) __builtin_amdgcn_mfma_f32_16x16x32_bf16((a), (b), (c), 0, 0, 0)

__device__ inline f32x4 zero4() {
    f32x4 z;
    z[0] = 0.f; z[1] = 0.f; z[2] = 0.f; z[3] = 0.f;
    return z;
}

__device__ inline unsigned short f2bf(float f) {
    unsigned u = __builtin_bit_cast(unsigned, f);
    u += 0x7fffu + ((u >> 16) & 1u);          // RNE
    return (unsigned short)(u >> 16);
}

__device__ inline short8 pack8(float4 a, float4 b) {
    short8 r;
    r[0] = (short)f2bf(a.x); r[1] = (short)f2bf(a.y); r[2] = (short)f2bf(a.z); r[3] = (short)f2bf(a.w);
    r[4] = (short)f2bf(b.x); r[5] = (short)f2bf(b.y); r[6] = (short)f2bf(b.z); r[7] = (short)f2bf(b.w);
    return r;
}

// ---------------- K1: voxelize scatter-add ----------------
__global__ void k_voxelize(const float* __restrict__ coords, const float* __restrict__ feats,
                           float* __restrict__ vsum, float* __restrict__ cnt) {
    int idx = blockIdx.x * 256 + threadIdx.x;
    int b = idx >> 15, n = idx & (N_ - 1);
    const float* cb = coords + (size_t)b * 3 * N_;
    float x = cb[n], y = cb[N_ + n], z = cb[2 * N_ + n];
    int vx = min(max((int)floorf(x * R_), 0), R_ - 1);
    int vy = min(max((int)floorf(y * R_), 0), R_ - 1);
    int vz = min(max((int)floorf(z * R_), 0), R_ - 1);
    int cell = (vx * R_ + vy) * R_ + vz;
    float* vs = vsum + (size_t)b * CIN * S_;
    const float* fb = feats + (size_t)b * CIN * N_;
#pragma unroll
    for (int f = 0; f < CIN; f++) atomicAdd(&vs[f * S_ + cell], fb[f * N_ + n]);
    atomicAdd(&cnt[b * S_ + cell], 1.0f);
}

// ---------------- K1b: divide by counts ----------------
__global__ void k_meandiv(float* __restrict__ vsum, const float* __restrict__ cnt) {
    int idx = blockIdx.x * 256 + threadIdx.x;
    int b = idx / (CIN * S_);
    int cell = idx & (S_ - 1);
    float c = cnt[b * S_ + cell];
    vsum[idx] = vsum[idx] / fmaxf(c, 1.0f);
}

// ---------------- K2: 3x3x3 conv + bias + relu -> vox [b][c][s] ----------------
__global__ void k_conv(const float* __restrict__ mean, const float* __restrict__ w,
                       const float* __restrict__ bias, float* __restrict__ outv) {
    __shared__ float wl[CIN * 27];
    int bo = blockIdx.x >> 4;
    int chunk = blockIdx.x & 15;
    int b = bo >> 6, o = bo & 63;
    if (threadIdx.x < CIN * 27) wl[threadIdx.x] = w[o * CIN * 27 + threadIdx.x];
    __syncthreads();
    int cell = chunk * 256 + threadIdx.x;
    int x = cell >> 8, y = (cell >> 4) & 15, z = cell & 15;
    const float* mb = mean + (size_t)b * CIN * S_;
    float acc = bias[o];
#pragma unroll
    for (int dx = 0; dx < 3; dx++) {
        int xx = x + dx - 1;
        if ((unsigned)xx >= (unsigned)R_) continue;
#pragma unroll
        for (int dy = 0; dy < 3; dy++) {
            int yy = y + dy - 1;
            if ((unsigned)yy >= (unsigned)R_) continue;
#pragma unroll
            for (int dz = 0; dz < 3; dz++) {
                int zz = z + dz - 1;
                if ((unsigned)zz >= (unsigned)R_) continue;
                int nc = (xx * 16 + yy) * 16 + zz;
#pragma unroll
                for (int i = 0; i < CIN; i++)
                    acc += wl[i * 27 + dx * 9 + dy * 3 + dz] * mb[i * S_ + nc];
            }
        }
    }
    outv[((size_t)b * 64 + o) * S_ + cell] = fmaxf(acc, 0.0f);
}

// ---------------- K3: qkv -> qT,kT bf16 [b][s][64]; vT bf16 [b][c][t]; voxT f32 [b][s][64] ----------------
__global__ __launch_bounds__(256) void k_qkv3(const float* __restrict__ x, const float* __restrict__ wq,
                                              const float* __restrict__ wk, const float* __restrict__ wv,
                                              unsigned short* __restrict__ qT, unsigned short* __restrict__ kT,
                                              unsigned short* __restrict__ vT, float* __restrict__ voxT) {
    __shared__ float wql[8 * 64], wkl[8 * 64], wvl[8 * 64];
    int bid = blockIdx.x;                 // b(4) x schunk(16) x osplit(8) = 512
    int b = bid >> 7;
    int schunk = (bid >> 3) & 15;
    int o0 = (bid & 7) * 8;
    int tid = threadIdx.x;
    for (int i = tid; i < 512; i += 256) {
        wql[i] = wq[o0 * 64 + i];
        wkl[i] = wk[o0 * 64 + i];
        wvl[i] = wv[o0 * 64 + i];
    }
    __syncthreads();
    int s = schunk * 256 + tid;
    const float* xb = x + (size_t)b * 64 * S_;
    float xr[64];
#pragma unroll
    for (int c = 0; c < 64; c++) xr[c] = xb[c * S_ + s];
    short8 sq, sk;
#pragma unroll
    for (int oj = 0; oj < 8; oj++) {
        float aq = 0.f, ak = 0.f, av = 0.f;
#pragma unroll
        for (int c = 0; c < 64; c++) {
            float xv = xr[c];
            aq += wql[oj * 64 + c] * xv;
            ak += wkl[oj * 64 + c] * xv;
            av += wvl[oj * 64 + c] * xv;
        }
        sq[oj] = (short)f2bf(aq);
        sk[oj] = (short)f2bf(ak);
        vT[((size_t)b * 64 + o0 + oj) * S_ + s] = f2bf(av);
    }
    *(short8*)(qT + ((size_t)b * S_ + s) * 64 + o0) = sq;
    *(short8*)(kT + ((size_t)b * S_ + s) * 64 + o0) = sk;
    if ((bid & 7) == 0) {
        float* vr = voxT + ((size_t)b * S_ + s) * 64;
#pragma unroll
        for (int i = 0; i < 16; i++)
            *(float4*)(vr + i * 4) = make_float4(xr[i * 4], xr[i * 4 + 1], xr[i * 4 + 2], xr[i * 4 + 3]);
    }
}

// ---------------- K4: flash attention, 1 wave/block, NO barriers (same-wave LDS ordering) ----------------
__global__ __launch_bounds__(64, 4) void k_attn5(const unsigned short* __restrict__ qT,
                                                 const unsigned short* __restrict__ kT,
                                                 const unsigned short* __restrict__ vT,
                                                 float* __restrict__ Opart, float* __restrict__ lpart) {
    __shared__ unsigned short Ps[16 * 64];
    int bid = blockIdx.x;                  // qtile(1024) x split(4)
    int split = bid & 3;
    int qtile = bid >> 2;
    int b = qtile >> 8;
    int sq0 = (qtile & 255) * 16;
    int lane = threadIdx.x;
    int lo = lane & 15, hi = lane >> 4;

    const unsigned short* qb = qT + ((size_t)b * S_ + sq0) * 64;
    bf16x8 qf0 = __builtin_bit_cast(bf16x8, *(const short8*)(qb + lo * 64 + hi * 8));
    bf16x8 qf1 = __builtin_bit_cast(bf16x8, *(const short8*)(qb + lo * 64 + hi * 8 + 32));

    f32x4 O[4];
    float l[4];
#pragma unroll
    for (int cc = 0; cc < 4; cc++) O[cc] = zero4();
#pragma unroll
    for (int j = 0; j < 4; j++) l[j] = 0.f;

    const unsigned short* kb = kT + (size_t)b * S_ * 64 + hi * 8;
    const unsigned short* vb = vT + (size_t)b * 64 * S_;

    for (int t0 = split * 1024; t0 < split * 1024 + 1024; t0 += 64) {
        // ---- V loads FIRST: no dependencies, latency hides under QK + softmax ----
        short8 vf0a, vf0b, vf1a, vf1b, vf2a, vf2b, vf3a, vf3b;
        {
            const unsigned short* vr0 = vb + (size_t)(0 * 16 + lo) * S_ + t0 + hi * 8;
            const unsigned short* vr1 = vb + (size_t)(1 * 16 + lo) * S_ + t0 + hi * 8;
            const unsigned short* vr2 = vb + (size_t)(2 * 16 + lo) * S_ + t0 + hi * 8;
            const unsigned short* vr3 = vb + (size_t)(3 * 16 + lo) * S_ + t0 + hi * 8;
            vf0a = *(const short8*)vr0; vf0b = *(const short8*)(vr0 + 32);
            vf1a = *(const short8*)vr1; vf1b = *(const short8*)(vr1 + 32);
            vf2a = *(const short8*)vr2; vf2b = *(const short8*)(vr2 + 32);
            vf3a = *(const short8*)vr3; vf3b = *(const short8*)(vr3 + 32);
        }
        // ---- K frags from global, QK^T ----
        f32x4 Sacc[4];
#pragma unroll
        for (int ct = 0; ct < 4; ct++) {
            const unsigned short* kr = kb + (size_t)(t0 + ct * 16 + lo) * 64;
            bf16x8 kf0 = __builtin_bit_cast(bf16x8, *(const short8*)kr);
            bf16x8 kf1 = __builtin_bit_cast(bf16x8, *(const short8*)(kr + 32));
            f32x4 z = zero4();
            z = MFMA16(qf0, kf0, z);
            Sacc[ct] = MFMA16(qf1, kf1, z);
        }
        // ---- fixed-max softmax: P = 2^(S * 0.125*log2e), lane-local l ----
#pragma unroll
        for (int j = 0; j < 4; j++) {
            int r = hi * 4 + j;
            int swz = (r & 7) << 4;
#pragma unroll
            for (int ct = 0; ct < 4; ct++) {
                float p = exp2f(Sacc[ct][j] * 0.18033688011112042f);
                l[j] += p;
                *(unsigned short*)((char*)Ps + ((r * 128 + (ct * 16 + lo) * 2) ^ swz)) = f2bf(p);
            }
        }
        // same wave: DS queue is in-order; no barrier needed before reading Ps
        int swz2 = (lo & 7) << 4;
        bf16x8 pa0 = __builtin_bit_cast(bf16x8, *(const short8*)((char*)Ps + ((lo * 128 + hi * 16) ^ swz2)));
        bf16x8 pa1 = __builtin_bit_cast(bf16x8, *(const short8*)((char*)Ps + ((lo * 128 + hi * 16 + 64) ^ swz2)));
        // ---- PV ----
        O[0] = MFMA16(pa0, __builtin_bit_cast(bf16x8, vf0a), O[0]);
        O[0] = MFMA16(pa1, __builtin_bit_cast(bf16x8, vf0b), O[0]);
        O[1] = MFMA16(pa0, __builtin_bit_cast(bf16x8, vf1a), O[1]);
        O[1] = MFMA16(pa1, __builtin_bit_cast(bf16x8, vf1b), O[1]);
        O[2] = MFMA16(pa0, __builtin_bit_cast(bf16x8, vf2a), O[2]);
        O[2] = MFMA16(pa1, __builtin_bit_cast(bf16x8, vf2b), O[2]);
        O[3] = MFMA16(pa0, __builtin_bit_cast(bf16x8, vf3a), O[3]);
        O[3] = MFMA16(pa1, __builtin_bit_cast(bf16x8, vf3b), O[3]);
    }

    // ---- write unnormalized partials + row sums ----
    float* ob = Opart + ((size_t)split * B_ * S_ + (size_t)b * S_ + sq0) * 64;
#pragma unroll
    for (int cc = 0; cc < 4; cc++)
#pragma unroll
        for (int j = 0; j < 4; j++)
            ob[(size_t)(hi * 4 + j) * 64 + cc * 16 + lo] = O[cc][j];
#pragma unroll
    for (int j = 0; j < 4; j++) {
        float s = l[j];
        s += __shfl_xor(s, 1);
        s += __shfl_xor(s, 2);
        s += __shfl_xor(s, 4);
        s += __shfl_xor(s, 8);
        if (lo == 0) lpart[(size_t)split * B_ * S_ + (size_t)b * S_ + sq0 + hi * 4 + j] = s;
    }
}

// ---------------- K5: combine(4 splits) + Wo MFMA + residual + SE-mean -> xattT ----------------
__global__ __launch_bounds__(256) void k_wo_mfma(const float* __restrict__ Opart,
                                                 const float* __restrict__ lpart,
                                                 const float* __restrict__ wo,
                                                 const float* __restrict__ voxT,
                                                 float* __restrict__ xattT,
                                                 float* __restrict__ semean) {
    __shared__ float sem[64];
    int tid = threadIdx.x;
    if (tid < 64) sem[tid] = 0.f;
    __syncthreads();
    int wid = tid >> 6, lane = tid & 63;
    int lo = lane & 15, hi = lane >> 4;
    int r0 = blockIdx.x * 64 + wid * 16;               // global row (b*S + s)
    int bidx = r0 >> 12;
    int row = r0 + lo;
    const int BS = B_ * S_;

    float L = lpart[row] + lpart[BS + row] + lpart[2 * BS + row] + lpart[3 * BS + row];
    float inv = 1.f / L;
    float4 q0 = make_float4(0.f, 0.f, 0.f, 0.f), q1 = q0, q2 = q0, q3 = q0;
#pragma unroll
    for (int sp = 0; sp < 4; sp++) {
        const float* orow = Opart + ((size_t)sp * BS + row) * 64 + hi * 8;
        float4 t0 = *(const float4*)(orow);
        float4 t1 = *(const float4*)(orow + 4);
        float4 t2 = *(const float4*)(orow + 32);
        float4 t3 = *(const float4*)(orow + 36);
        q0.x += t0.x; q0.y += t0.y; q0.z += t0.z; q0.w += t0.w;
        q1.x += t1.x; q1.y += t1.y; q1.z += t1.z; q1.w += t1.w;
        q2.x += t2.x; q2.y += t2.y; q2.z += t2.z; q2.w += t2.w;
        q3.x += t3.x; q3.y += t3.y; q3.z += t3.z; q3.w += t3.w;
    }
    q0.x *= inv; q0.y *= inv; q0.z *= inv; q0.w *= inv;
    q1.x *= inv; q1.y *= inv; q1.z *= inv; q1.w *= inv;
    q2.x *= inv; q2.y *= inv; q2.z *= inv; q2.w *= inv;
    q3.x *= inv; q3.y *= inv; q3.z *= inv; q3.w *= inv;
    bf16x8 a0 = __builtin_bit_cast(bf16x8, pack8(q0, q1));
    bf16x8 a1 = __builtin_bit_cast(bf16x8, pack8(q2, q3));

    float colsum[4];
#pragma unroll
    for (int cc = 0; cc < 4; cc++) {
        int o = cc * 16 + lo;
        float4 f0 = *(const float4*)(wo + o * 64 + hi * 8);
        float4 f1 = *(const float4*)(wo + o * 64 + hi * 8 + 4);
        bf16x8 b0 = __builtin_bit_cast(bf16x8, pack8(f0, f1));
        float4 f2 = *(const float4*)(wo + o * 64 + 32 + hi * 8);
        float4 f3 = *(const float4*)(wo + o * 64 + 32 + hi * 8 + 4);
        bf16x8 b1 = __builtin_bit_cast(bf16x8, pack8(f2, f3));
        f32x4 acc = zero4();
        acc = MFMA16(a0, b0, acc);
        acc = MFMA16(a1, b1, acc);
        float cs = 0.f;
#pragma unroll
        for (int j = 0; j < 4; j++) {
            size_t idx = (size_t)(r0 + hi * 4 + j) * 64 + o;
            float xn = acc[j] + voxT[idx];
            xattT[idx] = xn;
            cs += xn;
        }
        cs += __shfl_xor(cs, 16);
        cs += __shfl_xor(cs, 32);
        colsum[cc] = cs;
    }
    if (hi == 0) {
#pragma unroll
        for (int cc = 0; cc < 4; cc++) atomicAdd(&sem[cc * 16 + lo], colsum[cc]);
    }
    __syncthreads();
    if (tid < 64) atomicAdd(&semean[bidx * 64 + tid], sem[tid]);
}

// ---------------- K8: SE gate + devoxelize + point MLP + MFMA classifier ----------------
__global__ __launch_bounds__(256) void k_point(const float* __restrict__ coords, const float* __restrict__ feats,
                                               const float* __restrict__ xt, const float* __restrict__ semean,
                                               const float* __restrict__ sw1, const float* __restrict__ sb1,
                                               const float* __restrict__ sw2, const float* __restrict__ sb2,
                                               const float* __restrict__ pw,
                                               const float* __restrict__ pb, const float* __restrict__ w1,
                                               const float* __restrict__ b1, const float* __restrict__ w2,
                                               const float* __restrict__ b2, float* __restrict__ out) {
    __shared__ unsigned short fl[256 * 64];    // 32KB fused bf16, XOR-swizzled rows
    __shared__ float pwl[64 * 6];
    __shared__ float pbl[64];
    __shared__ float b1l[128];
    __shared__ float w2l[3 * 128];
    __shared__ float b2l[3];
    __shared__ float gl[64];
    __shared__ float sml[64];
    __shared__ float hh[8];
    int tid = threadIdx.x;
    int gidx0 = blockIdx.x * 256;
    int b = gidx0 >> 15, n0 = gidx0 & (N_ - 1);
    int n = n0 + tid;
    for (int i = tid; i < 384; i += 256) { pwl[i] = pw[i]; w2l[i] = w2[i]; }
    if (tid < 128) b1l[tid] = b1[tid];
    if (tid < 64) { pbl[tid] = pb[tid]; sml[tid] = semean[b * 64 + tid] * (1.0f / S_); }
    if (tid < 3) b2l[tid] = b2[tid];
    __syncthreads();
    if (tid < 8) {
        float a = sb1[tid];
#pragma unroll
        for (int i = 0; i < 64; i++) a += sw1[tid * 64 + i] * sml[i];
        hh[tid] = fmaxf(a, 0.f);
    }
    __syncthreads();
    if (tid < 64) {
        float g = sb2[tid];
#pragma unroll
        for (int j = 0; j < 8; j++) g += sw2[tid * 8 + j] * hh[j];
        gl[tid] = 1.f / (1.f + __expf(-g));
    }
    __syncthreads();

    // ---- phase 1: devoxelize gather + point MLP -> fused[64] ----
    const float* cb = coords + (size_t)b * 3 * N_;
    float px = fminf(fmaxf(cb[n] * R_ - 0.5f, 0.f), 15.f);
    float py = fminf(fmaxf(cb[N_ + n] * R_ - 0.5f, 0.f), 15.f);
    float pz = fminf(fmaxf(cb[2 * N_ + n] * R_ - 0.5f, 0.f), 15.f);
    int x0 = (int)floorf(px); float wx = px - x0; int x1 = min(x0 + 1, 15);
    int y0 = (int)floorf(py); float wy = py - y0; int y1 = min(y0 + 1, 15);
    int z0 = (int)floorf(pz); float wz = pz - z0; int z1 = min(z0 + 1, 15);
    float fused[64];
#pragma unroll
    for (int c = 0; c < 64; c++) fused[c] = 0.f;
    const float* xb = xt + (size_t)b * S_ * 64;
#pragma unroll
    for (int dx = 0; dx < 2; dx++) {
#pragma unroll
        for (int dy = 0; dy < 2; dy++) {
#pragma unroll
            for (int dz = 0; dz < 2; dz++) {
                int xi = dx ? x1 : x0, yi = dy ? y1 : y0, zi = dz ? z1 : z0;
                float wgt = (dx ? wx : 1.f - wx) * (dy ? wy : 1.f - wy) * (dz ? wz : 1.f - wz);
                const float4* g = (const float4*)(xb + (size_t)((xi * 16 + yi) * 16 + zi) * 64);
#pragma unroll
                for (int c4 = 0; c4 < 16; c4++) {
                    float4 gv = g[c4];
                    fused[c4 * 4 + 0] += wgt * gv.x;
                    fused[c4 * 4 + 1] += wgt * gv.y;
                    fused[c4 * 4 + 2] += wgt * gv.z;
                    fused[c4 * 4 + 3] += wgt * gv.w;
                }
            }
        }
    }
    float fv[6];
#pragma unroll
    for (int i = 0; i < 6; i++) fv[i] = feats[((size_t)b * 6 + i) * N_ + n];
#pragma unroll
    for (int c = 0; c < 64; c++) {
        float pt = pbl[c];
#pragma unroll
        for (int i = 0; i < 6; i++) pt += pwl[c * 6 + i] * fv[i];
        pt = fmaxf(pt, 0.f);
        fused[c] = fmaxf(fused[c] * gl[c] + pt, 0.f);
    }
    // write fused row (bf16, swizzled)
#pragma unroll
    for (int ch = 0; ch < 8; ch++) {
        short8 v;
#pragma unroll
        for (int i = 0; i < 8; i++) v[i] = (short)f2bf(fused[ch * 8 + i]);
        int byte = tid * 128 + ch * 16;
        *(short8*)((char*)fl + (byte ^ ((tid & 7) << 4))) = v;
    }
    __syncthreads();

    // ---- phase 2: MFMA classifier (per wave, 4 tiles of 16 points) ----
    int wv = tid >> 6, lane = tid & 63;
    int lo = lane & 15, hi = lane >> 4;
    // w1 B-frags: col = h = th*16+lo, k = c
    bf16x8 bw[16];
#pragma unroll
    for (int th = 0; th < 8; th++) {
#pragma unroll
        for (int kf = 0; kf < 2; kf++) {
            const float* wr = w1 + (th * 16 + lo) * 64 + kf * 32 + hi * 8;
            bw[th * 2 + kf] = __builtin_bit_cast(bf16x8, pack8(*(const float4*)wr, *(const float4*)(wr + 4)));
        }
    }
    float bb = b1l[hi * 8];  // dummy init; real loads below per th
    (void)bb;
#pragma unroll
    for (int g = 0; g < 4; g++) {
        int row = wv * 64 + g * 16 + lo;
        int swz = (row & 7) << 4;
        bf16x8 a0 = __builtin_bit_cast(bf16x8, *(const short8*)((char*)fl + ((row * 128 + hi * 16) ^ swz)));
        bf16x8 a1 = __builtin_bit_cast(bf16x8, *(const short8*)((char*)fl + ((row * 128 + 64 + hi * 16) ^ swz)));
        f32x4 acc[8];
#pragma unroll
        for (int th = 0; th < 8; th++) {
            acc[th] = zero4();
            acc[th] = MFMA16(a0, bw[th * 2], acc[th]);
            acc[th] = MFMA16(a1, bw[th * 2 + 1], acc[th]);
        }
        // D layout: lane holds h[point = hi*4+j][h = th*16+lo]
        float s0[4] = {0.f, 0.f, 0.f, 0.f};
        float s1[4] = {0.f, 0.f, 0.f, 0.f};
        float s2[4] = {0.f, 0.f, 0.f, 0.f};
#pragma unroll
        for (int th = 0; th < 8; th++) {
            int hidx = th * 16 + lo;
            float w2o0 = w2l[hidx];
            float w2o1 = w2l[128 + hidx];
            float w2o2 = w2l[256 + hidx];
            float bias = b1l[hidx];
#pragma unroll
            for (int j = 0; j < 4; j++) {
                float hj = fmaxf(acc[th][j] + bias, 0.f);
                s0[j] += hj * w2o0;
                s1[j] += hj * w2o1;
                s2[j] += hj * w2o2;
            }
        }
        // reduce over the 16 lanes (lo) of each hi-group
#pragma unroll
        for (int j = 0; j < 4; j++) {
            s0[j] += __shfl_xor(s0[j], 1); s0[j] += __shfl_xor(s0[j], 2);
            s0[j] += __shfl_xor(s0[j], 4); s0[j] += __shfl_xor(s0[j], 8);
            s1[j] += __shfl_xor(s1[j], 1); s1[j] += __shfl_xor(s1[j], 2);
            s1[j] += __shfl_xor(s1[j], 4); s1[j] += __shfl_xor(s1[j], 8);
            s2[j] += __shfl_xor(s2[j], 1); s2[j] += __shfl_xor(s2[j], 2);
            s2[j] += __shfl_xor(s2[j], 4); s2[j] += __shfl_xor(s2[j], 8);
        }
        int nbase = n0 + wv * 64 + g * 16 + hi * 4;
        if (lo == 0) {
            float4 o4 = make_float4(s0[0] + b2l[0], s0[1] + b2l[0], s0[2] + b2l[0], s0[3] + b2l[0]);
            *(float4*)(out + ((size_t)b * 3 + 0) * N_ + nbase) = o4;
        } else if (lo == 1) {
            float4 o4 = make_float4(s1[0] + b2l[1], s1[1] + b2l[1], s1[2] + b2l[1], s1[3] + b2l[1]);
            *(float4*)(out + ((size_t)b * 3 + 1) * N_ + nbase) = o4;
        } else if (lo == 2) {
            float4 o4 = make_float4(s2[0] + b2l[2], s2[1] + b2l[2], s2[2] + b2l[2], s2[3] + b2l[2]);
            *(float4*)(out + ((size_t)b * 3 + 2) * N_ + nbase) = o4;
        }
    }
}

extern "C" void kernel_launch(void* const* d_in, const int* in_sizes, int n_in,
                              void* d_out, int out_size, void* d_ws, size_t ws_size,
                              hipStream_t stream) {
    const float* coords  = (const float*)d_in[0];
    const float* feats   = (const float*)d_in[1];
    const float* conv_w  = (const float*)d_in[2];
    const float* conv_b  = (const float*)d_in[3];
    const float* wq      = (const float*)d_in[4];
    const float* wk      = (const float*)d_in[5];
    const float* wv      = (const float*)d_in[6];
    const float* wo      = (const float*)d_in[7];
    const float* se_w1   = (const float*)d_in[8];
    const float* se_b1   = (const float*)d_in[9];
    const float* se_w2   = (const float*)d_in[10];
    const float* se_b2   = (const float*)d_in[11];
    const float* point_w = (const float*)d_in[12];
    const float* point_b = (const float*)d_in[13];
    const float* cls_w1  = (const float*)d_in[14];
    const float* cls_b1  = (const float*)d_in[15];
    const float* cls_w2  = (const float*)d_in[16];
    const float* cls_b2  = (const float*)d_in[17];

    float* ws = (float*)d_ws;
    float* vsum   = ws;                        // 98304
    float* cnt    = ws + 98304;                // 16384
    float* semean = ws + 114688;               // 256
    float* vox    = ws + 115200;               // 1048576  [conv -> qkv3]; reused as xattT
    float* voxT   = vox + 1048576;             // 1048576  [qkv3 -> wo]
    unsigned short* qT = (unsigned short*)(voxT + 1048576);   // bf16
    unsigned short* kT = qT + 1048576;
    unsigned short* vT = kT + 1048576;
    float* Opart  = (float*)(vT + 1048576);    // 4 x 16384 x 64
    float* lpart  = Opart + 4194304;           // 65536
    float* xattT  = vox;

    hipMemsetAsync(ws, 0, 114944 * sizeof(float), stream);
    k_voxelize<<<512, 256, 0, stream>>>(coords, feats, vsum, cnt);
    k_meandiv<<<384, 256, 0, stream>>>(vsum, cnt);
    k_conv<<<4096, 256, 0, stream>>>(vsum, conv_w, conv_b, vox);
    k_qkv3<<<512, 256, 0, stream>>>(vox, wq, wk, wv, qT, kT, vT, voxT);
    k_attn5<<<4096, 64, 0, stream>>>(qT, kT, vT, Opart, lpart);
    k_wo_mfma<<<256, 256, 0, stream>>>(Opart, lpart, wo, voxT, xattT, semean);
    k_point<<<512, 256, 0, stream>>>(coords, feats, xattT, semean,
                                     se_w1, se_b1, se_w2, se_b2, point_w, point_b,
                                     cls_w1, cls_b1, cls_w2, cls_b2, (float*)d_out);
}

// Round 8
// 241.344 us; speedup vs baseline: 3.9914x; 1.2405x over previous
//
#include <hip/hip_runtime.h>
#include <hip/hip_bf16.h>
#include <math.h>

#define B_ 4
#define N_ 32768
#define CIN 6
#define C_ 64
#define R_ 16
#define S_ 4096

typedef __attribute__((ext_vector_type(8))) __bf16 bf16x8;
typedef __attribute__((ext_vector_type(8))) short short8;
typedef __attribute__((ext_vector_type(4))) float f32x4;

#define MFMA16(a, b, c) __builtin_amdgcn_mfma_f32_16x16x32_bf16((a), (b), (c), 0, 0, 0)

__device__ inline f32x4 zero4() {
    f32x4 z;
    z[0] = 0.f; z[1] = 0.f; z[2] = 0.f; z[3] = 0.f;
    return z;
}

__device__ inline unsigned short f2bf(float f) {
    unsigned u = __builtin_bit_cast(unsigned, f);
    u += 0x7fffu + ((u >> 16) & 1u);          // RNE
    return (unsigned short)(u >> 16);
}

__device__ inline short8 pack8(float4 a, float4 b) {
    short8 r;
    r[0] = (short)f2bf(a.x); r[1] = (short)f2bf(a.y); r[2] = (short)f2bf(a.z); r[3] = (short)f2bf(a.w);
    r[4] = (short)f2bf(b.x); r[5] = (short)f2bf(b.y); r[6] = (short)f2bf(b.z); r[7] = (short)f2bf(b.w);
    return r;
}

// ---------------- K1: voxelize scatter-add ----------------
__global__ void k_voxelize(const float* __restrict__ coords, const float* __restrict__ feats,
                           float* __restrict__ vsum, float* __restrict__ cnt) {
    int idx = blockIdx.x * 256 + threadIdx.x;
    int b = idx >> 15, n = idx & (N_ - 1);
    const float* cb = coords + (size_t)b * 3 * N_;
    float x = cb[n], y = cb[N_ + n], z = cb[2 * N_ + n];
    int vx = min(max((int)floorf(x * R_), 0), R_ - 1);
    int vy = min(max((int)floorf(y * R_), 0), R_ - 1);
    int vz = min(max((int)floorf(z * R_), 0), R_ - 1);
    int cell = (vx * R_ + vy) * R_ + vz;
    float* vs = vsum + (size_t)b * CIN * S_;
    const float* fb = feats + (size_t)b * CIN * N_;
#pragma unroll
    for (int f = 0; f < CIN; f++) atomicAdd(&vs[f * S_ + cell], fb[f * N_ + n]);
    atomicAdd(&cnt[b * S_ + cell], 1.0f);
}

// ---------------- K1b: divide by counts ----------------
__global__ void k_meandiv(float* __restrict__ vsum, const float* __restrict__ cnt) {
    int idx = blockIdx.x * 256 + threadIdx.x;
    int b = idx / (CIN * S_);
    int cell = idx & (S_ - 1);
    float c = cnt[b * S_ + cell];
    vsum[idx] = vsum[idx] / fmaxf(c, 1.0f);
}

// ---------------- K2: 3x3x3 conv + bias + relu -> vox [b][c][s] ----------------
__global__ void k_conv(const float* __restrict__ mean, const float* __restrict__ w,
                       const float* __restrict__ bias, float* __restrict__ outv) {
    __shared__ float wl[CIN * 27];
    int bo = blockIdx.x >> 4;
    int chunk = blockIdx.x & 15;
    int b = bo >> 6, o = bo & 63;
    if (threadIdx.x < CIN * 27) wl[threadIdx.x] = w[o * CIN * 27 + threadIdx.x];
    __syncthreads();
    int cell = chunk * 256 + threadIdx.x;
    int x = cell >> 8, y = (cell >> 4) & 15, z = cell & 15;
    const float* mb = mean + (size_t)b * CIN * S_;
    float acc = bias[o];
#pragma unroll
    for (int dx = 0; dx < 3; dx++) {
        int xx = x + dx - 1;
        if ((unsigned)xx >= (unsigned)R_) continue;
#pragma unroll
        for (int dy = 0; dy < 3; dy++) {
            int yy = y + dy - 1;
            if ((unsigned)yy >= (unsigned)R_) continue;
#pragma unroll
            for (int dz = 0; dz < 3; dz++) {
                int zz = z + dz - 1;
                if ((unsigned)zz >= (unsigned)R_) continue;
                int nc = (xx * 16 + yy) * 16 + zz;
#pragma unroll
                for (int i = 0; i < CIN; i++)
                    acc += wl[i * 27 + dx * 9 + dy * 3 + dz] * mb[i * S_ + nc];
            }
        }
    }
    outv[((size_t)b * 64 + o) * S_ + cell] = fmaxf(acc, 0.0f);
}

// ---------------- K3: qkv -> qT,kT bf16 [b][s][64]; vT bf16 [b][c][t]; voxT f32 [b][s][64] ----------------
__global__ __launch_bounds__(256) void k_qkv3(const float* __restrict__ x, const float* __restrict__ wq,
                                              const float* __restrict__ wk, const float* __restrict__ wv,
                                              unsigned short* __restrict__ qT, unsigned short* __restrict__ kT,
                                              unsigned short* __restrict__ vT, float* __restrict__ voxT) {
    __shared__ float wql[8 * 64], wkl[8 * 64], wvl[8 * 64];
    int bid = blockIdx.x;                 // b(4) x schunk(16) x osplit(8) = 512
    int b = bid >> 7;
    int schunk = (bid >> 3) & 15;
    int o0 = (bid & 7) * 8;
    int tid = threadIdx.x;
    for (int i = tid; i < 512; i += 256) {
        wql[i] = wq[o0 * 64 + i];
        wkl[i] = wk[o0 * 64 + i];
        wvl[i] = wv[o0 * 64 + i];
    }
    __syncthreads();
    int s = schunk * 256 + tid;
    const float* xb = x + (size_t)b * 64 * S_;
    float xr[64];
#pragma unroll
    for (int c = 0; c < 64; c++) xr[c] = xb[c * S_ + s];
    short8 sq, sk;
#pragma unroll
    for (int oj = 0; oj < 8; oj++) {
        float aq = 0.f, ak = 0.f, av = 0.f;
#pragma unroll
        for (int c = 0; c < 64; c++) {
            float xv = xr[c];
            aq += wql[oj * 64 + c] * xv;
            ak += wkl[oj * 64 + c] * xv;
            av += wvl[oj * 64 + c] * xv;
        }
        sq[oj] = (short)f2bf(aq);
        sk[oj] = (short)f2bf(ak);
        vT[((size_t)b * 64 + o0 + oj) * S_ + s] = f2bf(av);
    }
    *(short8*)(qT + ((size_t)b * S_ + s) * 64 + o0) = sq;
    *(short8*)(kT + ((size_t)b * S_ + s) * 64 + o0) = sk;
    if ((bid & 7) == 0) {
        float* vr = voxT + ((size_t)b * S_ + s) * 64;
#pragma unroll
        for (int i = 0; i < 16; i++)
            *(float4*)(vr + i * 4) = make_float4(xr[i * 4], xr[i * 4 + 1], xr[i * 4 + 2], xr[i * 4 + 3]);
    }
}

// ---------------- K4: flash attention — 32 q-rows/wave, 4 waves = 4 KV-splits, in-LDS combine ----------------
__global__ __launch_bounds__(256, 2) void k_attn6(const unsigned short* __restrict__ qT,
                                                  const unsigned short* __restrict__ kT,
                                                  const unsigned short* __restrict__ vT,
                                                  unsigned short* __restrict__ pvT) {
    __shared__ unsigned short Ps[4][2048];     // per-wave 32x64 bf16, swizzled
    __shared__ float Oc[4][2048];              // per-wave 32x64 f32 partials
    __shared__ float lc[4][32];                // per-wave row sums
    int bid = blockIdx.x;                      // 512: b(4) x qtile(128)
    int b = bid >> 7;
    int sq0 = (bid & 127) * 32;
    int tid = threadIdx.x;
    int w = tid >> 6, lane = tid & 63;
    int lo = lane & 15, hi = lane >> 4;

    // Q fragments for 2 sub-tiles of 16 rows
    const unsigned short* qb = qT + ((size_t)b * S_ + sq0) * 64;
    bf16x8 qf00 = __builtin_bit_cast(bf16x8, *(const short8*)(qb + lo * 64 + hi * 8));
    bf16x8 qf01 = __builtin_bit_cast(bf16x8, *(const short8*)(qb + lo * 64 + hi * 8 + 32));
    bf16x8 qf10 = __builtin_bit_cast(bf16x8, *(const short8*)(qb + (16 + lo) * 64 + hi * 8));
    bf16x8 qf11 = __builtin_bit_cast(bf16x8, *(const short8*)(qb + (16 + lo) * 64 + hi * 8 + 32));

    f32x4 O[8];
    float l[8];
#pragma unroll
    for (int i = 0; i < 8; i++) O[i] = zero4();
#pragma unroll
    for (int i = 0; i < 8; i++) l[i] = 0.f;

    const unsigned short* kb = kT + (size_t)b * S_ * 64 + hi * 8;
    const unsigned short* vb = vT + (size_t)b * 64 * S_;

    for (int t0 = w * 1024; t0 < w * 1024 + 1024; t0 += 64) {
        // ---- V loads first: independent, hide under QK + softmax ----
        short8 vfa0, vfb0, vfa1, vfb1, vfa2, vfb2, vfa3, vfb3;
        {
            const unsigned short* vr0 = vb + (size_t)(0 + lo) * S_ + t0 + hi * 8;
            const unsigned short* vr1 = vb + (size_t)(16 + lo) * S_ + t0 + hi * 8;
            const unsigned short* vr2 = vb + (size_t)(32 + lo) * S_ + t0 + hi * 8;
            const unsigned short* vr3 = vb + (size_t)(48 + lo) * S_ + t0 + hi * 8;
            vfa0 = *(const short8*)vr0; vfb0 = *(const short8*)(vr0 + 32);
            vfa1 = *(const short8*)vr1; vfb1 = *(const short8*)(vr1 + 32);
            vfa2 = *(const short8*)vr2; vfb2 = *(const short8*)(vr2 + 32);
            vfa3 = *(const short8*)vr3; vfb3 = *(const short8*)(vr3 + 32);
        }
        // ---- QK^T + fixed-max softmax, per 16-col tile ----
#pragma unroll
        for (int ct = 0; ct < 4; ct++) {
            const unsigned short* kr = kb + (size_t)(t0 + ct * 16 + lo) * 64;
            bf16x8 kf0 = __builtin_bit_cast(bf16x8, *(const short8*)kr);
            bf16x8 kf1 = __builtin_bit_cast(bf16x8, *(const short8*)(kr + 32));
#pragma unroll
            for (int qs = 0; qs < 2; qs++) {
                f32x4 z = zero4();
                z = MFMA16(qs ? qf10 : qf00, kf0, z);
                f32x4 Sacc = MFMA16(qs ? qf11 : qf01, kf1, z);
#pragma unroll
                for (int j = 0; j < 4; j++) {
                    float p = __expf(Sacc[j] * 0.125f);
                    l[qs * 4 + j] += p;
                    int r = qs * 16 + hi * 4 + j;
                    int swz = (r & 7) << 4;
                    *(unsigned short*)((char*)&Ps[w][0] + ((r * 128 + (ct * 16 + lo) * 2) ^ swz)) = f2bf(p);
                }
            }
        }
        // ---- PV: P A-frags from LDS (same-wave ordering), V frags in regs ----
#pragma unroll
        for (int qs = 0; qs < 2; qs++) {
            int row = qs * 16 + lo;
            int swz2 = (row & 7) << 4;
            bf16x8 pa0 = __builtin_bit_cast(bf16x8, *(const short8*)((char*)&Ps[w][0] + ((row * 128 + hi * 16) ^ swz2)));
            bf16x8 pa1 = __builtin_bit_cast(bf16x8, *(const short8*)((char*)&Ps[w][0] + ((row * 128 + 64 + hi * 16) ^ swz2)));
            O[qs * 4 + 0] = MFMA16(pa0, __builtin_bit_cast(bf16x8, vfa0), O[qs * 4 + 0]);
            O[qs * 4 + 0] = MFMA16(pa1, __builtin_bit_cast(bf16x8, vfb0), O[qs * 4 + 0]);
            O[qs * 4 + 1] = MFMA16(pa0, __builtin_bit_cast(bf16x8, vfa1), O[qs * 4 + 1]);
            O[qs * 4 + 1] = MFMA16(pa1, __builtin_bit_cast(bf16x8, vfb1), O[qs * 4 + 1]);
            O[qs * 4 + 2] = MFMA16(pa0, __builtin_bit_cast(bf16x8, vfa2), O[qs * 4 + 2]);
            O[qs * 4 + 2] = MFMA16(pa1, __builtin_bit_cast(bf16x8, vfb2), O[qs * 4 + 2]);
            O[qs * 4 + 3] = MFMA16(pa0, __builtin_bit_cast(bf16x8, vfa3), O[qs * 4 + 3]);
            O[qs * 4 + 3] = MFMA16(pa1, __builtin_bit_cast(bf16x8, vfb3), O[qs * 4 + 3]);
        }
    }

    // ---- dump partials to LDS ----
#pragma unroll
    for (int qs = 0; qs < 2; qs++)
#pragma unroll
        for (int cc = 0; cc < 4; cc++)
#pragma unroll
            for (int j = 0; j < 4; j++)
                Oc[w][(qs * 16 + hi * 4 + j) * 64 + cc * 16 + lo] = O[qs * 4 + cc][j];
#pragma unroll
    for (int qs = 0; qs < 2; qs++)
#pragma unroll
        for (int j = 0; j < 4; j++) {
            float s = l[qs * 4 + j];
            s += __shfl_xor(s, 1);
            s += __shfl_xor(s, 2);
            s += __shfl_xor(s, 4);
            s += __shfl_xor(s, 8);
            if (lo == 0) lc[w][qs * 16 + hi * 4 + j] = s;
        }
    __syncthreads();

    // ---- combine 4 splits, normalize, write bf16 pvT ----
    {
        int row = tid >> 3;                  // 0..31
        int c0 = (tid & 7) * 8;
        float L = lc[0][row] + lc[1][row] + lc[2][row] + lc[3][row];
        float inv = 1.f / L;
        int base = row * 64 + c0;
        float4 u0, u1;
        u0.x = (Oc[0][base + 0] + Oc[1][base + 0] + Oc[2][base + 0] + Oc[3][base + 0]) * inv;
        u0.y = (Oc[0][base + 1] + Oc[1][base + 1] + Oc[2][base + 1] + Oc[3][base + 1]) * inv;
        u0.z = (Oc[0][base + 2] + Oc[1][base + 2] + Oc[2][base + 2] + Oc[3][base + 2]) * inv;
        u0.w = (Oc[0][base + 3] + Oc[1][base + 3] + Oc[2][base + 3] + Oc[3][base + 3]) * inv;
        u1.x = (Oc[0][base + 4] + Oc[1][base + 4] + Oc[2][base + 4] + Oc[3][base + 4]) * inv;
        u1.y = (Oc[0][base + 5] + Oc[1][base + 5] + Oc[2][base + 5] + Oc[3][base + 5]) * inv;
        u1.z = (Oc[0][base + 6] + Oc[1][base + 6] + Oc[2][base + 6] + Oc[3][base + 6]) * inv;
        u1.w = (Oc[0][base + 7] + Oc[1][base + 7] + Oc[2][base + 7] + Oc[3][base + 7]) * inv;
        *(short8*)(pvT + ((size_t)b * S_ + sq0 + row) * 64 + c0) = pack8(u0, u1);
    }
}

// ---------------- K5: Wo via MFMA + residual + SE-mean partials -> xattT f32 [row][64] ----------------
__global__ __launch_bounds__(256) void k_wo_mfma(const unsigned short* __restrict__ pvT,
                                                 const float* __restrict__ wo,
                                                 const float* __restrict__ voxT,
                                                 float* __restrict__ xattT,
                                                 float* __restrict__ semean) {
    __shared__ float sem[64];
    int tid = threadIdx.x;
    if (tid < 64) sem[tid] = 0.f;
    __syncthreads();
    int wid = tid >> 6, lane = tid & 63;
    int lo = lane & 15, hi = lane >> 4;
    int r0 = blockIdx.x * 64 + wid * 16;               // global row (b*S + s)
    int bidx = r0 >> 12;

    const unsigned short* ar = pvT + (size_t)(r0 + lo) * 64 + hi * 8;
    bf16x8 a0 = __builtin_bit_cast(bf16x8, *(const short8*)ar);
    bf16x8 a1 = __builtin_bit_cast(bf16x8, *(const short8*)(ar + 32));

    float colsum[4];
#pragma unroll
    for (int cc = 0; cc < 4; cc++) {
        int o = cc * 16 + lo;
        float4 f0 = *(const float4*)(wo + o * 64 + hi * 8);
        float4 f1 = *(const float4*)(wo + o * 64 + hi * 8 + 4);
        bf16x8 b0 = __builtin_bit_cast(bf16x8, pack8(f0, f1));
        float4 f2 = *(const float4*)(wo + o * 64 + 32 + hi * 8);
        float4 f3 = *(const float4*)(wo + o * 64 + 32 + hi * 8 + 4);
        bf16x8 b1 = __builtin_bit_cast(bf16x8, pack8(f2, f3));
        f32x4 acc = zero4();
        acc = MFMA16(a0, b0, acc);
        acc = MFMA16(a1, b1, acc);
        float cs = 0.f;
#pragma unroll
        for (int j = 0; j < 4; j++) {
            size_t idx = (size_t)(r0 + hi * 4 + j) * 64 + o;
            float xn = acc[j] + voxT[idx];
            xattT[idx] = xn;
            cs += xn;
        }
        cs += __shfl_xor(cs, 16);
        cs += __shfl_xor(cs, 32);
        colsum[cc] = cs;
    }
    if (hi == 0) {
#pragma unroll
        for (int cc = 0; cc < 4; cc++) atomicAdd(&sem[cc * 16 + lo], colsum[cc]);
    }
    __syncthreads();
    if (tid < 64) atomicAdd(&semean[bidx * 64 + tid], sem[tid]);
}

// ---------------- K8: SE gate + devoxelize + point MLP + MFMA classifier ----------------
__global__ __launch_bounds__(256) void k_point(const float* __restrict__ coords, const float* __restrict__ feats,
                                               const float* __restrict__ xt, const float* __restrict__ semean,
                                               const float* __restrict__ sw1, const float* __restrict__ sb1,
                                               const float* __restrict__ sw2, const float* __restrict__ sb2,
                                               const float* __restrict__ pw,
                                               const float* __restrict__ pb, const float* __restrict__ w1,
                                               const float* __restrict__ b1, const float* __restrict__ w2,
                                               const float* __restrict__ b2, float* __restrict__ out) {
    __shared__ unsigned short fl[256 * 64];    // 32KB fused bf16, XOR-swizzled rows
    __shared__ float pwl[64 * 6];
    __shared__ float pbl[64];
    __shared__ float b1l[128];
    __shared__ float w2l[3 * 128];
    __shared__ float b2l[3];
    __shared__ float gl[64];
    __shared__ float sml[64];
    __shared__ float hh[8];
    int tid = threadIdx.x;
    int gidx0 = blockIdx.x * 256;
    int b = gidx0 >> 15, n0 = gidx0 & (N_ - 1);
    int n = n0 + tid;
    for (int i = tid; i < 384; i += 256) { pwl[i] = pw[i]; w2l[i] = w2[i]; }
    if (tid < 128) b1l[tid] = b1[tid];
    if (tid < 64) { pbl[tid] = pb[tid]; sml[tid] = semean[b * 64 + tid] * (1.0f / S_); }
    if (tid < 3) b2l[tid] = b2[tid];
    __syncthreads();
    if (tid < 8) {
        float a = sb1[tid];
#pragma unroll
        for (int i = 0; i < 64; i++) a += sw1[tid * 64 + i] * sml[i];
        hh[tid] = fmaxf(a, 0.f);
    }
    __syncthreads();
    if (tid < 64) {
        float g = sb2[tid];
#pragma unroll
        for (int j = 0; j < 8; j++) g += sw2[tid * 8 + j] * hh[j];
        gl[tid] = 1.f / (1.f + __expf(-g));
    }
    __syncthreads();

    // ---- phase 1: devoxelize gather + point MLP -> fused[64] ----
    const float* cb = coords + (size_t)b * 3 * N_;
    float px = fminf(fmaxf(cb[n] * R_ - 0.5f, 0.f), 15.f);
    float py = fminf(fmaxf(cb[N_ + n] * R_ - 0.5f, 0.f), 15.f);
    float pz = fminf(fmaxf(cb[2 * N_ + n] * R_ - 0.5f, 0.f), 15.f);
    int x0 = (int)floorf(px); float wx = px - x0; int x1 = min(x0 + 1, 15);
    int y0 = (int)floorf(py); float wy = py - y0; int y1 = min(y0 + 1, 15);
    int z0 = (int)floorf(pz); float wz = pz - z0; int z1 = min(z0 + 1, 15);
    float fused[64];
#pragma unroll
    for (int c = 0; c < 64; c++) fused[c] = 0.f;
    const float* xb = xt + (size_t)b * S_ * 64;
#pragma unroll
    for (int dx = 0; dx < 2; dx++) {
#pragma unroll
        for (int dy = 0; dy < 2; dy++) {
#pragma unroll
            for (int dz = 0; dz < 2; dz++) {
                int xi = dx ? x1 : x0, yi = dy ? y1 : y0, zi = dz ? z1 : z0;
                float wgt = (dx ? wx : 1.f - wx) * (dy ? wy : 1.f - wy) * (dz ? wz : 1.f - wz);
                const float4* g = (const float4*)(xb + (size_t)((xi * 16 + yi) * 16 + zi) * 64);
#pragma unroll
                for (int c4 = 0; c4 < 16; c4++) {
                    float4 gv = g[c4];
                    fused[c4 * 4 + 0] += wgt * gv.x;
                    fused[c4 * 4 + 1] += wgt * gv.y;
                    fused[c4 * 4 + 2] += wgt * gv.z;
                    fused[c4 * 4 + 3] += wgt * gv.w;
                }
            }
        }
    }
    float fv[6];
#pragma unroll
    for (int i = 0; i < 6; i++) fv[i] = feats[((size_t)b * 6 + i) * N_ + n];
#pragma unroll
    for (int c = 0; c < 64; c++) {
        float pt = pbl[c];
#pragma unroll
        for (int i = 0; i < 6; i++) pt += pwl[c * 6 + i] * fv[i];
        pt = fmaxf(pt, 0.f);
        fused[c] = fmaxf(fused[c] * gl[c] + pt, 0.f);
    }
    // write fused row (bf16, swizzled)
#pragma unroll
    for (int ch = 0; ch < 8; ch++) {
        short8 v;
#pragma unroll
        for (int i = 0; i < 8; i++) v[i] = (short)f2bf(fused[ch * 8 + i]);
        int byte = tid * 128 + ch * 16;
        *(short8*)((char*)fl + (byte ^ ((tid & 7) << 4))) = v;
    }
    __syncthreads();

    // ---- phase 2: MFMA classifier (per wave, 4 tiles of 16 points) ----
    int wv = tid >> 6, lane = tid & 63;
    int lo = lane & 15, hi = lane >> 4;
    bf16x8 bw[16];
#pragma unroll
    for (int th = 0; th < 8; th++) {
#pragma unroll
        for (int kf = 0; kf < 2; kf++) {
            const float* wr = w1 + (th * 16 + lo) * 64 + kf * 32 + hi * 8;
            bw[th * 2 + kf] = __builtin_bit_cast(bf16x8, pack8(*(const float4*)wr, *(const float4*)(wr + 4)));
        }
    }
#pragma unroll
    for (int g = 0; g < 4; g++) {
        int row = wv * 64 + g * 16 + lo;
        int swz = (row & 7) << 4;
        bf16x8 a0 = __builtin_bit_cast(bf16x8, *(const short8*)((char*)fl + ((row * 128 + hi * 16) ^ swz)));
        bf16x8 a1 = __builtin_bit_cast(bf16x8, *(const short8*)((char*)fl + ((row * 128 + 64 + hi * 16) ^ swz)));
        f32x4 acc[8];
#pragma unroll
        for (int th = 0; th < 8; th++) {
            acc[th] = zero4();
            acc[th] = MFMA16(a0, bw[th * 2], acc[th]);
            acc[th] = MFMA16(a1, bw[th * 2 + 1], acc[th]);
        }
        float s0[4] = {0.f, 0.f, 0.f, 0.f};
        float s1[4] = {0.f, 0.f, 0.f, 0.f};
        float s2[4] = {0.f, 0.f, 0.f, 0.f};
#pragma unroll
        for (int th = 0; th < 8; th++) {
            int hidx = th * 16 + lo;
            float w2o0 = w2l[hidx];
            float w2o1 = w2l[128 + hidx];
            float w2o2 = w2l[256 + hidx];
            float bias = b1l[hidx];
#pragma unroll
            for (int j = 0; j < 4; j++) {
                float hj = fmaxf(acc[th][j] + bias, 0.f);
                s0[j] += hj * w2o0;
                s1[j] += hj * w2o1;
                s2[j] += hj * w2o2;
            }
        }
#pragma unroll
        for (int j = 0; j < 4; j++) {
            s0[j] += __shfl_xor(s0[j], 1); s0[j] += __shfl_xor(s0[j], 2);
            s0[j] += __shfl_xor(s0[j], 4); s0[j] += __shfl_xor(s0[j], 8);
            s1[j] += __shfl_xor(s1[j], 1); s1[j] += __shfl_xor(s1[j], 2);
            s1[j] += __shfl_xor(s1[j], 4); s1[j] += __shfl_xor(s1[j], 8);
            s2[j] += __shfl_xor(s2[j], 1); s2[j] += __shfl_xor(s2[j], 2);
            s2[j] += __shfl_xor(s2[j], 4); s2[j] += __shfl_xor(s2[j], 8);
        }
        int nbase = n0 + wv * 64 + g * 16 + hi * 4;
        if (lo == 0) {
            float4 o4 = make_float4(s0[0] + b2l[0], s0[1] + b2l[0], s0[2] + b2l[0], s0[3] + b2l[0]);
            *(float4*)(out + ((size_t)b * 3 + 0) * N_ + nbase) = o4;
        } else if (lo == 1) {
            float4 o4 = make_float4(s1[0] + b2l[1], s1[1] + b2l[1], s1[2] + b2l[1], s1[3] + b2l[1]);
            *(float4*)(out + ((size_t)b * 3 + 1) * N_ + nbase) = o4;
        } else if (lo == 2) {
            float4 o4 = make_float4(s2[0] + b2l[2], s2[1] + b2l[2], s2[2] + b2l[2], s2[3] + b2l[2]);
            *(float4*)(out + ((size_t)b * 3 + 2) * N_ + nbase) = o4;
        }
    }
}

extern "C" void kernel_launch(void* const* d_in, const int* in_sizes, int n_in,
                              void* d_out, int out_size, void* d_ws, size_t ws_size,
                              hipStream_t stream) {
    const float* coords  = (const float*)d_in[0];
    const float* feats   = (const float*)d_in[1];
    const float* conv_w  = (const float*)d_in[2];
    const float* conv_b  = (const float*)d_in[3];
    const float* wq      = (const float*)d_in[4];
    const float* wk      = (const float*)d_in[5];
    const float* wv      = (const float*)d_in[6];
    const float* wo      = (const float*)d_in[7];
    const float* se_w1   = (const float*)d_in[8];
    const float* se_b1   = (const float*)d_in[9];
    const float* se_w2   = (const float*)d_in[10];
    const float* se_b2   = (const float*)d_in[11];
    const float* point_w = (const float*)d_in[12];
    const float* point_b = (const float*)d_in[13];
    const float* cls_w1  = (const float*)d_in[14];
    const float* cls_b1  = (const float*)d_in[15];
    const float* cls_w2  = (const float*)d_in[16];
    const float* cls_b2  = (const float*)d_in[17];

    float* ws = (float*)d_ws;
    float* vsum   = ws;                        // 98304
    float* cnt    = ws + 98304;                // 16384
    float* semean = ws + 114688;               // 256
    float* vox    = ws + 115200;               // 1048576 [conv -> qkv3]; reused as xattT
    float* voxT   = vox + 1048576;             // 1048576 [qkv3 -> wo]
    unsigned short* qT = (unsigned short*)(voxT + 1048576);   // bf16, 524288 fl each
    unsigned short* kT = qT + 1048576;
    unsigned short* vT = kT + 1048576;
    unsigned short* pvT = vT + 1048576;        // bf16
    float* xattT  = vox;                       // vox dead after k_qkv3

    hipMemsetAsync(ws, 0, 114944 * sizeof(float), stream);    // vsum + cnt + semean
    k_voxelize<<<512, 256, 0, stream>>>(coords, feats, vsum, cnt);
    k_meandiv<<<384, 256, 0, stream>>>(vsum, cnt);
    k_conv<<<4096, 256, 0, stream>>>(vsum, conv_w, conv_b, vox);
    k_qkv3<<<512, 256, 0, stream>>>(vox, wq, wk, wv, qT, kT, vT, voxT);
    k_attn6<<<512, 256, 0, stream>>>(qT, kT, vT, pvT);
    k_wo_mfma<<<256, 256, 0, stream>>>(pvT, wo, voxT, xattT, semean);
    k_point<<<512, 256, 0, stream>>>(coords, feats, xattT, semean,
                                     se_w1, se_b1, se_w2, se_b2, point_w, point_b,
                                     cls_w1, cls_b1, cls_w2, cls_b2, (float*)d_out);
}